// Round 1
// baseline (681.087 us; speedup 1.0000x reference)
//
#include <hip/hip_runtime.h>
#include <math.h>

#define N_NODE 100000
#define N_EDGE 1000000
#define DIM    64
#define NB     256
#define NVOCAB 401

// Y[r][lane] = (bias?bias[lane]:0) + dot(W[lane][:], X[idx?idx[r]:r][:]), optional relu.
// One wave (64 lanes) per output row; input row broadcast via shuffles.
// Safe for in-place (X==Y) since the row is register-held before the write.
__global__ __launch_bounds__(256) void matvec64_kernel(
    const float* __restrict__ X,
    const int*   __restrict__ idx,
    const float* __restrict__ W,
    const float* __restrict__ bias,
    float* __restrict__ Y,
    int R, int relu_flag)
{
    int w    = (blockIdx.x * blockDim.x + threadIdx.x) >> 6;
    int lane = threadIdx.x & 63;
    if (w >= R) return;
    int row = idx ? idx[w] : w;
    float x = X[(size_t)row * DIM + lane];
    const float4* W4 = (const float4*)W;
    float acc = bias ? bias[lane] : 0.0f;
    #pragma unroll
    for (int k4 = 0; k4 < 16; ++k4) {
        float4 wv = W4[lane * 16 + k4];
        acc += wv.x * __shfl(x, k4 * 4 + 0);
        acc += wv.y * __shfl(x, k4 * 4 + 1);
        acc += wv.z * __shfl(x, k4 * 4 + 2);
        acc += wv.w * __shfl(x, k4 * 4 + 3);
    }
    if (relu_flag) acc = fmaxf(acc, 0.0f);
    Y[(size_t)w * DIM + lane] = acc;
}

// One wave per edge; lane = feature dim.
template<int USE_HW>
__global__ __launch_bounds__(256) void edge_kernel(
    const int*   __restrict__ edges,
    const float* __restrict__ hidden,
    const float* __restrict__ rela,
    const float* __restrict__ hiddenWs,  // [N_NODE][64] precomputed hidden@Ws^T (if USE_HW)
    const float* __restrict__ Ws,        // used if !USE_HW
    const float* __restrict__ rel_pre,   // [NVOCAB][64] rela@Wr^T
    const float* __restrict__ qr_pre,    // [NB][64] rela[q_rel]@Wqr^T + b
    const float* __restrict__ wattn,     // [64]
    float* __restrict__ out)             // [N_NODE][64] accumulator (pre-zeroed)
{
    int e = (blockIdx.x * blockDim.x + threadIdx.x) >> 6;
    if (e >= N_EDGE) return;
    int lane = threadIdx.x & 63;

    int r_idx = edges[e * 6 + 0];
    int rel   = edges[e * 6 + 2];
    int sub   = edges[e * 6 + 4];
    int obj   = edges[e * 6 + 5];

    float hs = hidden[(size_t)sub * DIM + lane];
    float hr = rela[(size_t)rel * DIM + lane];

    float pre = rel_pre[rel * DIM + lane] + qr_pre[r_idx * DIM + lane];
    if (USE_HW) {
        pre += hiddenWs[(size_t)sub * DIM + lane];
    } else {
        const float4* W4 = (const float4*)Ws;
        float acc = 0.0f;
        #pragma unroll
        for (int k4 = 0; k4 < 16; ++k4) {
            float4 wv = W4[lane * 16 + k4];
            acc += wv.x * __shfl(hs, k4 * 4 + 0);
            acc += wv.y * __shfl(hs, k4 * 4 + 1);
            acc += wv.z * __shfl(hs, k4 * 4 + 2);
            acc += wv.w * __shfl(hs, k4 * 4 + 3);
        }
        pre += acc;
    }

    // alpha = sigmoid(sum_a wattn[a] * relu(pre[a]))
    float t = wattn[lane] * fmaxf(pre, 0.0f);
    #pragma unroll
    for (int off = 32; off; off >>= 1) t += __shfl_xor(t, off);
    float alpha = 1.0f / (1.0f + __expf(-t));

    // mobius/exp/log maps are identity to O(1e-6) at c=1e-6
    float msg = (hs + hr) * alpha;
    atomicAdd(&out[(size_t)obj * DIM + lane], msg);
}

extern "C" void kernel_launch(void* const* d_in, const int* in_sizes, int n_in,
                              void* d_out, int out_size, void* d_ws, size_t ws_size,
                              hipStream_t stream)
{
    const float* hidden = (const float*)d_in[0];
    const int*   q_rel  = (const int*)  d_in[1];
    const int*   edges  = (const int*)  d_in[2];
    const float* rela   = (const float*)d_in[3];
    const float* Ws     = (const float*)d_in[4];
    const float* Wr     = (const float*)d_in[5];
    const float* Wqr    = (const float*)d_in[6];
    const float* Wqr_b  = (const float*)d_in[7];
    const float* Wattn  = (const float*)d_in[8];
    const float* Wh     = (const float*)d_in[9];
    float* out = (float*)d_out;

    float* qr_pre   = (float*)d_ws;             // 256*64
    float* rel_pre  = qr_pre + NB * DIM;        // 401*64
    float* hiddenWs = rel_pre + NVOCAB * DIM;   // 100000*64
    size_t need_hw = (size_t)(NB + NVOCAB + N_NODE) * DIM * sizeof(float);
    bool use_hw = ws_size >= need_hw;

    // zero the accumulator (harness poisons d_out with 0xAA)
    hipMemsetAsync(d_out, 0, (size_t)N_NODE * DIM * sizeof(float), stream);

    // precompute tables
    matvec64_kernel<<<(NB + 3) / 4, 256, 0, stream>>>(rela, q_rel, Wqr, Wqr_b, qr_pre, NB, 0);
    matvec64_kernel<<<(NVOCAB + 3) / 4, 256, 0, stream>>>(rela, nullptr, Wr, nullptr, rel_pre, NVOCAB, 0);
    if (use_hw) {
        matvec64_kernel<<<(N_NODE + 3) / 4, 256, 0, stream>>>(hidden, nullptr, Ws, nullptr, hiddenWs, N_NODE, 0);
    }

    // main per-edge kernel: 1 wave per edge
    int edge_blocks = (N_EDGE + 3) / 4;
    if (use_hw) {
        edge_kernel<1><<<edge_blocks, 256, 0, stream>>>(edges, hidden, rela, hiddenWs, Ws,
                                                        rel_pre, qr_pre, Wattn, out);
    } else {
        edge_kernel<0><<<edge_blocks, 256, 0, stream>>>(edges, hidden, rela, nullptr, Ws,
                                                        rel_pre, qr_pre, Wattn, out);
    }

    // out = relu(agg @ Wh^T), in-place
    matvec64_kernel<<<(N_NODE + 3) / 4, 256, 0, stream>>>(out, nullptr, Wh, nullptr, out, N_NODE, 1);
}

// Round 2
// 594.813 us; speedup vs baseline: 1.1450x; 1.1450x over previous
//
#include <hip/hip_runtime.h>
#include <math.h>

#define N_NODE 100000
#define N_EDGE 1000000
#define DIM    64
#define NB     256
#define NVOCAB 401
#define SCAN_B 1024
#define NCHUNK ((N_NODE + SCAN_B - 1) / SCAN_B)

// ---------------------------------------------------------------------------
// Fast 64x64 matvec: Y[r] = relu?(W @ X[idx?idx[r]:r] + bias)
// One wave per 64 rows. Rows staged coalesced into XOR-swizzled LDS, then
// transposed into per-lane registers (lane n holds row n). W[j][k] is
// wave-uniform -> scalar loads. 4 DS ops/row vs 64 shuffles/row.
// In-place safe (each wave reads only the rows it writes).
// ---------------------------------------------------------------------------
__global__ __launch_bounds__(256) void matvec_fast(
    const float* __restrict__ X,
    const int*   __restrict__ idx,
    const float* __restrict__ W,
    const float* __restrict__ bias,
    float* __restrict__ Y,
    int R, int relu_flag)
{
    __shared__ float tile[4][64 * 64];   // 64 KB/block, XOR-swizzled
    int wid  = threadIdx.x >> 6;
    int lane = threadIdx.x & 63;
    int r0   = __builtin_amdgcn_readfirstlane((blockIdx.x * 4 + wid) * 64);
    float* t = tile[wid];

    // stage 64 rows, coalesced; element (i, c) at t[i*64 + (c ^ i)]
    #pragma unroll 4
    for (int i = 0; i < 64; ++i) {
        int r = r0 + i;
        float v = 0.0f;
        if (r < R) {
            int src = idx ? idx[r] : r;
            v = X[(size_t)src * DIM + lane];
        }
        t[i * 64 + (lane ^ i)] = v;
    }
    __syncthreads();

    // lane n pulls its row into registers (conflict-free: bank = (k^n)%32)
    float x[64];
    #pragma unroll
    for (int k = 0; k < 64; ++k) x[k] = t[lane * 64 + (k ^ lane)];

    // out[n][j] = dot(W[j], x) ; W uniform -> s_loads
    for (int j = 0; j < 64; ++j) {
        float acc = bias ? bias[j] : 0.0f;
        #pragma unroll
        for (int k = 0; k < 64; ++k) acc = fmaf(W[j * 64 + k], x[k], acc);
        if (relu_flag) acc = fmaxf(acc, 0.0f);
        t[lane * 64 + (j ^ lane)] = acc;   // row=lane, col=j
    }
    __syncthreads();

    // coalesced store
    #pragma unroll 4
    for (int i = 0; i < 64; ++i) {
        int r = r0 + i;
        if (r < R) Y[(size_t)r * DIM + lane] = t[i * 64 + (lane ^ i)];
    }
}

// ---------------------------------------------------------------------------
// CSR build
// ---------------------------------------------------------------------------
__global__ __launch_bounds__(256) void deg_kernel(const int* __restrict__ edges,
                                                  int* __restrict__ deg)
{
    int e = blockIdx.x * blockDim.x + threadIdx.x;
    if (e < N_EDGE) atomicAdd(&deg[edges[e * 6 + 5]], 1);
}

__global__ __launch_bounds__(SCAN_B) void scan1_kernel(const int* __restrict__ deg,
                                                       int* __restrict__ partial)
{
    __shared__ int s[SCAN_B];
    int g = blockIdx.x * SCAN_B + threadIdx.x;
    s[threadIdx.x] = (g < N_NODE) ? deg[g] : 0;
    __syncthreads();
    for (int off = SCAN_B / 2; off; off >>= 1) {
        if (threadIdx.x < off) s[threadIdx.x] += s[threadIdx.x + off];
        __syncthreads();
    }
    if (threadIdx.x == 0) partial[blockIdx.x] = s[0];
}

__global__ void scan2_kernel(int* __restrict__ partial, int n)
{
    // single thread; n = 98
    int acc = 0;
    for (int i = 0; i < n; ++i) { int v = partial[i]; partial[i] = acc; acc += v; }
}

__global__ __launch_bounds__(SCAN_B) void scan3_kernel(const int* __restrict__ deg,
                                                       const int* __restrict__ partial,
                                                       int* __restrict__ offs)
{
    __shared__ int s[SCAN_B];
    int g = blockIdx.x * SCAN_B + threadIdx.x;
    int v = (g < N_NODE) ? deg[g] : 0;
    s[threadIdx.x] = v;
    __syncthreads();
    // Hillis-Steele inclusive scan
    for (int off = 1; off < SCAN_B; off <<= 1) {
        int add = (threadIdx.x >= (unsigned)off) ? s[threadIdx.x - off] : 0;
        __syncthreads();
        s[threadIdx.x] += add;
        __syncthreads();
    }
    if (g < N_NODE) {
        offs[g + 1] = partial[blockIdx.x] + s[threadIdx.x];
        if (g == 0) offs[0] = 0;
    }
}

__global__ __launch_bounds__(256) void scatter_kernel(const int* __restrict__ edges,
                                                      const int* __restrict__ offs,
                                                      int* __restrict__ cursor,
                                                      int* __restrict__ csr)
{
    int e = blockIdx.x * blockDim.x + threadIdx.x;
    if (e < N_EDGE) {
        int o = edges[e * 6 + 5];
        int slot = offs[o] + atomicAdd(&cursor[o], 1);
        csr[slot] = e;
    }
}

// ---------------------------------------------------------------------------
// Aggregation: one wave per node, atomic-free, 1-edge software prefetch.
// All indices wave-uniform -> scalar loads; gathers are coalesced 256B rows.
// ---------------------------------------------------------------------------
__global__ __launch_bounds__(256) void agg_kernel(
    const int*   __restrict__ edges,
    const int*   __restrict__ offs,
    const int*   __restrict__ csr,
    const float* __restrict__ hidden,
    const float* __restrict__ rela,
    const float* __restrict__ hsWs,     // [N_NODE][64] hidden@Ws^T
    const float* __restrict__ rel_pre,  // [NVOCAB][64]
    const float* __restrict__ qr_pre,   // [NB][64]
    const float* __restrict__ wattn,    // [64]
    float* __restrict__ out)            // [N_NODE][64]
{
    int wv = (blockIdx.x * blockDim.x + threadIdx.x) >> 6;
    int n = __builtin_amdgcn_readfirstlane(wv);
    if (n >= N_NODE) return;
    int lane = threadIdx.x & 63;

    int i   = offs[n];
    int end = offs[n + 1];
    float wat = wattn[lane];
    float acc = 0.0f;

    if (i < end) {
        int eid = csr[i];
        int r_i = edges[eid * 6 + 0];
        int rl  = edges[eid * 6 + 2];
        int sb  = edges[eid * 6 + 4];
        float c_p1 = hsWs[(size_t)sb * DIM + lane];
        float c_p2 = rel_pre[rl * DIM + lane];
        float c_p3 = qr_pre[r_i * DIM + lane];
        float c_h  = hidden[(size_t)sb * DIM + lane];
        float c_r  = rela[rl * DIM + lane];

        while (i < end) {
            int ni = i + 1;
            float n_p1, n_p2, n_p3, n_h, n_r;
            if (ni < end) {  // wave-uniform branch: prefetch next edge
                int eid2 = csr[ni];
                int r2  = edges[eid2 * 6 + 0];
                int rl2 = edges[eid2 * 6 + 2];
                int sb2 = edges[eid2 * 6 + 4];
                n_p1 = hsWs[(size_t)sb2 * DIM + lane];
                n_p2 = rel_pre[rl2 * DIM + lane];
                n_p3 = qr_pre[r2 * DIM + lane];
                n_h  = hidden[(size_t)sb2 * DIM + lane];
                n_r  = rela[rl2 * DIM + lane];
            } else {
                n_p1 = n_p2 = n_p3 = n_h = n_r = 0.0f;
            }
            // alpha = sigmoid( wattn . relu(pre) )
            float t = wat * fmaxf(c_p1 + c_p2 + c_p3, 0.0f);
            #pragma unroll
            for (int off = 32; off; off >>= 1) t += __shfl_xor(t, off);
            float alpha = 1.0f / (1.0f + __expf(-t));
            // hyperbolic maps are identity to O(c)=1e-6 at c=1e-6
            acc = fmaf(alpha, c_h + c_r, acc);

            c_p1 = n_p1; c_p2 = n_p2; c_p3 = n_p3; c_h = n_h; c_r = n_r;
            i = ni;
        }
    }
    out[(size_t)n * DIM + lane] = acc;
}

// ---------------------------------------------------------------------------
// Fallback: atomic per-edge kernel (used only if d_ws too small for CSR)
// ---------------------------------------------------------------------------
template<int USE_HW>
__global__ __launch_bounds__(256) void edge_kernel(
    const int*   __restrict__ edges,
    const float* __restrict__ hidden,
    const float* __restrict__ rela,
    const float* __restrict__ hsWs,
    const float* __restrict__ Ws,
    const float* __restrict__ rel_pre,
    const float* __restrict__ qr_pre,
    const float* __restrict__ wattn,
    float* __restrict__ out)
{
    int e = (blockIdx.x * blockDim.x + threadIdx.x) >> 6;
    if (e >= N_EDGE) return;
    int lane = threadIdx.x & 63;
    int r_i = edges[e * 6 + 0];
    int rl  = edges[e * 6 + 2];
    int sb  = edges[e * 6 + 4];
    int ob  = edges[e * 6 + 5];
    float hs = hidden[(size_t)sb * DIM + lane];
    float hr = rela[(size_t)rl * DIM + lane];
    float pre = rel_pre[rl * DIM + lane] + qr_pre[r_i * DIM + lane];
    if (USE_HW) {
        pre += hsWs[(size_t)sb * DIM + lane];
    } else {
        const float4* W4 = (const float4*)Ws;
        float a = 0.0f;
        #pragma unroll
        for (int k4 = 0; k4 < 16; ++k4) {
            float4 wv = W4[lane * 16 + k4];
            a += wv.x * __shfl(hs, k4 * 4 + 0);
            a += wv.y * __shfl(hs, k4 * 4 + 1);
            a += wv.z * __shfl(hs, k4 * 4 + 2);
            a += wv.w * __shfl(hs, k4 * 4 + 3);
        }
        pre += a;
    }
    float t = wattn[lane] * fmaxf(pre, 0.0f);
    #pragma unroll
    for (int off = 32; off; off >>= 1) t += __shfl_xor(t, off);
    float alpha = 1.0f / (1.0f + __expf(-t));
    atomicAdd(&out[(size_t)ob * DIM + lane], (hs + hr) * alpha);
}

extern "C" void kernel_launch(void* const* d_in, const int* in_sizes, int n_in,
                              void* d_out, int out_size, void* d_ws, size_t ws_size,
                              hipStream_t stream)
{
    const float* hidden = (const float*)d_in[0];
    const int*   q_rel  = (const int*)  d_in[1];
    const int*   edges  = (const int*)  d_in[2];
    const float* rela   = (const float*)d_in[3];
    const float* Ws     = (const float*)d_in[4];
    const float* Wr     = (const float*)d_in[5];
    const float* Wqr    = (const float*)d_in[6];
    const float* Wqr_b  = (const float*)d_in[7];
    const float* Wattn  = (const float*)d_in[8];
    const float* Wh     = (const float*)d_in[9];
    float* out = (float*)d_out;

    // workspace layout
    float* qr_pre  = (float*)d_ws;               // NB*64
    float* rel_pre = qr_pre + NB * DIM;          // NVOCAB*64
    float* hsWs    = rel_pre + NVOCAB * DIM;     // N_NODE*64
    size_t float_need = (size_t)(NB + NVOCAB + N_NODE) * DIM * sizeof(float);
    int* deg     = (int*)((char*)d_ws + float_need);  // N_NODE
    int* cursor  = deg + N_NODE;                      // N_NODE (contiguous w/ deg)
    int* offs    = cursor + N_NODE;                   // N_NODE+1
    int* partial = offs + (N_NODE + 1);               // NCHUNK
    int* csr     = partial + ((NCHUNK + 63) & ~63);   // N_EDGE
    size_t csr_need = float_need +
        ((size_t)(2 * N_NODE + N_NODE + 1 + ((NCHUNK + 63) & ~63) + N_EDGE)) * sizeof(int);

    bool use_hw  = ws_size >= float_need;
    bool use_csr = ws_size >= csr_need;

    // small precompute tables
    matvec_fast<<<1, 256, 0, stream>>>(rela, q_rel, Wqr, Wqr_b, qr_pre, NB, 0);
    matvec_fast<<<2, 256, 0, stream>>>(rela, nullptr, Wr, nullptr, rel_pre, NVOCAB, 0);
    if (use_hw)
        matvec_fast<<<(N_NODE + 255) / 256, 256, 0, stream>>>(hidden, nullptr, Ws, nullptr,
                                                              hsWs, N_NODE, 0);

    if (use_csr) {
        // CSR build
        hipMemsetAsync(deg, 0, 2 * N_NODE * sizeof(int), stream);  // deg + cursor
        deg_kernel<<<(N_EDGE + 255) / 256, 256, 0, stream>>>(edges, deg);
        scan1_kernel<<<NCHUNK, SCAN_B, 0, stream>>>(deg, partial);
        scan2_kernel<<<1, 1, 0, stream>>>(partial, NCHUNK);
        scan3_kernel<<<NCHUNK, SCAN_B, 0, stream>>>(deg, partial, offs);
        scatter_kernel<<<(N_EDGE + 255) / 256, 256, 0, stream>>>(edges, offs, cursor, csr);
        // atomic-free aggregation, one wave per node
        agg_kernel<<<(N_NODE * 64 + 255) / 256, 256, 0, stream>>>(
            edges, offs, csr, hidden, rela, hsWs, rel_pre, qr_pre, Wattn, out);
    } else {
        hipMemsetAsync(d_out, 0, (size_t)N_NODE * DIM * sizeof(float), stream);
        int eb = (N_EDGE + 3) / 4;
        if (use_hw)
            edge_kernel<1><<<eb, 256, 0, stream>>>(edges, hidden, rela, hsWs, Ws,
                                                   rel_pre, qr_pre, Wattn, out);
        else
            edge_kernel<0><<<eb, 256, 0, stream>>>(edges, hidden, rela, nullptr, Ws,
                                                   rel_pre, qr_pre, Wattn, out);
    }

    // out = relu(agg @ Wh^T), in-place (logmap0 ~ identity at c=1e-6)
    matvec_fast<<<(N_NODE + 255) / 256, 256, 0, stream>>>(out, nullptr, Wh, nullptr,
                                                          out, N_NODE, 1);
}

// Round 4
// 364.710 us; speedup vs baseline: 1.8675x; 1.6309x over previous
//
#include <hip/hip_runtime.h>
#include <math.h>
#include <stdint.h>

#define N_NODE 100000
#define N_EDGE 1000000
#define DIM    64
#define NB     256
#define NVOCAB 401
#define SCAN_B 1024
#define NCHUNK ((N_NODE + SCAN_B - 1) / SCAN_B)

typedef short short8  __attribute__((ext_vector_type(8)));
typedef float floatx4 __attribute__((ext_vector_type(4)));

// ---------------------------------------------------------------------------
// gemm64: Y[r][:] = relu?( X[idx?idx[r]:r] @ W^T + bias ),  W is 64x64 row-major
// (Y[r][j] = sum_k X[src][k] * W[j][k]).
// MFMA 16x16x32 bf16, split-bf16 (hi/lo) 3-term product => ~fp32 precision.
// Block = 256 thr = 4 waves; block covers 16 rows x 64 cols (wave w -> cols 16w..).
// A frag: A[m=lane&15][k=quad*8+j]  (A row = X row r0+m)
// B frag: B[k=quad*8+j][n=lane&15]  (B col n = W row n0+n  -> read W[n0+m][k])
// C/D:    col=lane&15, row=quad*4+reg
// In-place safe: all operand loads complete before __syncthreads(); stores after.
// ---------------------------------------------------------------------------
__device__ inline void split8(float4 v0, float4 v1, short8& hi, short8& lo)
{
    float f[8] = {v0.x, v0.y, v0.z, v0.w, v1.x, v1.y, v1.z, v1.w};
    #pragma unroll
    for (int j = 0; j < 8; ++j) {
        unsigned u = __float_as_uint(f[j]);
        unsigned r = u + 0x7FFF + ((u >> 16) & 1);      // RNE to bf16
        unsigned short h = (unsigned short)(r >> 16);
        float hf = __uint_as_float(((unsigned)h) << 16);
        float l  = f[j] - hf;
        unsigned u2 = __float_as_uint(l);
        unsigned r2 = u2 + 0x7FFF + ((u2 >> 16) & 1);
        hi[j] = (short)h;
        lo[j] = (short)(r2 >> 16);
    }
}

__global__ __launch_bounds__(256) void gemm64_kernel(
    const float* __restrict__ X,
    const int*   __restrict__ idx,
    const float* __restrict__ W,
    const float* __restrict__ bias,
    float* __restrict__ Y,
    int R, int relu_flag)
{
    int wave = threadIdx.x >> 6;     // 0..3 -> output col group n0 = wave*16
    int lane = threadIdx.x & 63;
    int m    = lane & 15;
    int quad = lane >> 4;
    int r0   = blockIdx.x * 16;
    int n0   = wave * 16;

    int r = r0 + m;
    int src = (r < R) ? (idx ? idx[r] : r) : 0;   // clamp; garbage rows never stored

    const float* xrow = X + (size_t)src * DIM + quad * 8;
    const float* wrow = W + (size_t)(n0 + m) * DIM + quad * 8;   // B col n0+m

    // ---- load ALL operands first (in-place safety across waves) ----
    float4 a[2][2], b[2][2];
    #pragma unroll
    for (int c = 0; c < 2; ++c) {
        a[c][0] = *(const float4*)(xrow + 32 * c);
        a[c][1] = *(const float4*)(xrow + 32 * c + 4);
        b[c][0] = *(const float4*)(wrow + 32 * c);
        b[c][1] = *(const float4*)(wrow + 32 * c + 4);
    }
    float bv = bias ? bias[n0 + m] : 0.0f;
    __syncthreads();   // all reads of X complete before any wave stores to Y(==X)

    floatx4 acc = {0.f, 0.f, 0.f, 0.f};
    #pragma unroll
    for (int c = 0; c < 2; ++c) {
        short8 ah, al, bh, bl;
        split8(a[c][0], a[c][1], ah, al);
        split8(b[c][0], b[c][1], bh, bl);
        acc = __builtin_amdgcn_mfma_f32_16x16x32_bf16(ah, bh, acc, 0, 0, 0);
        acc = __builtin_amdgcn_mfma_f32_16x16x32_bf16(ah, bl, acc, 0, 0, 0);
        acc = __builtin_amdgcn_mfma_f32_16x16x32_bf16(al, bh, acc, 0, 0, 0);
    }

    #pragma unroll
    for (int g = 0; g < 4; ++g) {
        int rr = r0 + quad * 4 + g;             // D row = quad*4 + reg
        if (rr < R) {
            float v = acc[g] + bv;              // D col = lane&15 = m -> out col n0+m
            if (relu_flag) v = fmaxf(v, 0.0f);
            Y[(size_t)rr * DIM + n0 + m] = v;
        }
    }
}

// ---------------------------------------------------------------------------
// CSR build
// ---------------------------------------------------------------------------
__global__ __launch_bounds__(256) void deg_kernel(const int* __restrict__ edges,
                                                  int* __restrict__ deg)
{
    int e = blockIdx.x * blockDim.x + threadIdx.x;
    if (e < N_EDGE) {
        int2 so = *(const int2*)(edges + (size_t)e * 6 + 4);  // (sub, obj)
        atomicAdd(&deg[so.y], 1);
    }
}

__global__ __launch_bounds__(SCAN_B) void scan1_kernel(const int* __restrict__ deg,
                                                       int* __restrict__ partial)
{
    __shared__ int s[SCAN_B];
    int g = blockIdx.x * SCAN_B + threadIdx.x;
    s[threadIdx.x] = (g < N_NODE) ? deg[g] : 0;
    __syncthreads();
    for (int off = SCAN_B / 2; off; off >>= 1) {
        if (threadIdx.x < off) s[threadIdx.x] += s[threadIdx.x + off];
        __syncthreads();
    }
    if (threadIdx.x == 0) partial[blockIdx.x] = s[0];
}

__global__ void scan2_kernel(int* __restrict__ partial, int n)
{
    int acc = 0;
    for (int i = 0; i < n; ++i) { int v = partial[i]; partial[i] = acc; acc += v; }
}

__global__ __launch_bounds__(SCAN_B) void scan3_kernel(const int* __restrict__ deg,
                                                       const int* __restrict__ partial,
                                                       int* __restrict__ offs)
{
    __shared__ int s[SCAN_B];
    int g = blockIdx.x * SCAN_B + threadIdx.x;
    s[threadIdx.x] = (g < N_NODE) ? deg[g] : 0;
    __syncthreads();
    for (int off = 1; off < SCAN_B; off <<= 1) {
        int add = ((int)threadIdx.x >= off) ? s[threadIdx.x - off] : 0;
        __syncthreads();
        s[threadIdx.x] += add;
        __syncthreads();
    }
    if (g < N_NODE) {
        offs[g + 1] = partial[blockIdx.x] + s[threadIdx.x];
        if (g == 0) offs[0] = 0;
    }
}

// scatter: emit packed csr2[slot] = (sub, rel<<8 | r_idx)   (rel<512, r_idx<256)
// Thread 0 also writes the pad slot csr2[N_EDGE] = (0,0) every call — the agg
// kernel overreads one slot for odd-degree tails and d_ws is re-poisoned 0xAA
// before every launch (a poisoned pad index caused R3's memory fault).
__global__ __launch_bounds__(256) void scatter_kernel(const int* __restrict__ edges,
                                                      const int* __restrict__ offs,
                                                      int* __restrict__ cursor,
                                                      int2* __restrict__ csr2)
{
    int e = blockIdx.x * blockDim.x + threadIdx.x;
    if (e == 0) csr2[N_EDGE] = make_int2(0, 0);
    if (e < N_EDGE) {
        int2 ab = *(const int2*)(edges + (size_t)e * 6);      // (r_idx, 0)
        int2 cd = *(const int2*)(edges + (size_t)e * 6 + 2);  // (rel, 0)
        int2 ef = *(const int2*)(edges + (size_t)e * 6 + 4);  // (sub, obj)
        int slot = offs[ef.y] + atomicAdd(&cursor[ef.y], 1);
        csr2[slot] = make_int2(ef.x, (cd.x << 8) | ab.x);
    }
}

// ---------------------------------------------------------------------------
// Aggregation v2: one wave per node, 2 edges per iteration.
// lane = (half, feature-pair): half-wave h processes edge i+h over 32 float2
// feature lanes. 5 dwordx2 row loads per edge, 5-shfl reduce serves both edges.
// ---------------------------------------------------------------------------
__global__ __launch_bounds__(256) void agg_kernel(
    const int2*  __restrict__ csr2,     // [N_EDGE+1] (pad slot written by scatter)
    const int*   __restrict__ offs,
    const float* __restrict__ hidden,
    const float* __restrict__ rela,
    const float* __restrict__ hsWs,
    const float* __restrict__ rel_pre,
    const float* __restrict__ qr_pre,
    const float* __restrict__ wattn,
    float* __restrict__ out)
{
    int wv = (blockIdx.x * blockDim.x + threadIdx.x) >> 6;
    int n  = __builtin_amdgcn_readfirstlane(wv);
    if (n >= N_NODE) return;
    int lane = threadIdx.x & 63;
    int half = lane >> 5;
    int fl   = lane & 31;               // features 2*fl, 2*fl+1

    float2 wat = *(const float2*)(wattn + 2 * fl);
    float2 acc = make_float2(0.f, 0.f);

    int i   = offs[n];
    int end = offs[n + 1];

    while (i < end) {
        int2 e0 = csr2[i];              // wave-uniform
        int2 e1 = csr2[i + 1];          // pad slot (0,0) makes this always safe
        float valid = (half == 0 || i + 1 < end) ? 1.0f : 0.0f;
        int sub = half ? e1.x : e0.x;
        int pk  = half ? e1.y : e0.y;
        int rl  = pk >> 8;
        int ri  = pk & 255;

        float2 p1 = *((const float2*)(hsWs    + (size_t)sub * DIM) + fl);
        float2 p2 = *((const float2*)(rel_pre + (size_t)rl  * DIM) + fl);
        float2 p3 = *((const float2*)(qr_pre  + (size_t)ri  * DIM) + fl);
        float2 h  = *((const float2*)(hidden  + (size_t)sub * DIM) + fl);
        float2 rv = *((const float2*)(rela    + (size_t)rl  * DIM) + fl);

        float t = fmaxf(p1.x + p2.x + p3.x, 0.f) * wat.x
                + fmaxf(p1.y + p2.y + p3.y, 0.f) * wat.y;
        #pragma unroll
        for (int off = 16; off; off >>= 1) t += __shfl_xor(t, off);  // within half
        float alpha = valid / (1.0f + __expf(-t));

        // hyperbolic maps are identity to O(c)=1e-6 at c=1e-6
        acc.x = fmaf(alpha, h.x + rv.x, acc.x);
        acc.y = fmaf(alpha, h.y + rv.y, acc.y);
        i += 2;
    }

    // combine the two halves' partial sums (same feature pair)
    acc.x += __shfl_xor(acc.x, 32);
    acc.y += __shfl_xor(acc.y, 32);
    if (half == 0)
        *((float2*)(out + (size_t)n * DIM) + fl) = acc;
}

// ---------------------------------------------------------------------------
// Fallback: atomic per-edge kernel (only if d_ws too small for CSR)
// ---------------------------------------------------------------------------
__global__ __launch_bounds__(256) void edge_kernel(
    const int*   __restrict__ edges,
    const float* __restrict__ hidden,
    const float* __restrict__ rela,
    const float* __restrict__ hsWs,
    const float* __restrict__ rel_pre,
    const float* __restrict__ qr_pre,
    const float* __restrict__ wattn,
    float* __restrict__ out)
{
    int e = (blockIdx.x * blockDim.x + threadIdx.x) >> 6;
    if (e >= N_EDGE) return;
    int lane = threadIdx.x & 63;
    int r_i = edges[e * 6 + 0];
    int rl  = edges[e * 6 + 2];
    int sb  = edges[e * 6 + 4];
    int ob  = edges[e * 6 + 5];
    float hs = hidden[(size_t)sb * DIM + lane];
    float hr = rela[(size_t)rl * DIM + lane];
    float pre = hsWs[(size_t)sb * DIM + lane] + rel_pre[rl * DIM + lane]
              + qr_pre[r_i * DIM + lane];
    float t = wattn[lane] * fmaxf(pre, 0.0f);
    #pragma unroll
    for (int off = 32; off; off >>= 1) t += __shfl_xor(t, off);
    float alpha = 1.0f / (1.0f + __expf(-t));
    atomicAdd(&out[(size_t)ob * DIM + lane], (hs + hr) * alpha);
}

extern "C" void kernel_launch(void* const* d_in, const int* in_sizes, int n_in,
                              void* d_out, int out_size, void* d_ws, size_t ws_size,
                              hipStream_t stream)
{
    const float* hidden = (const float*)d_in[0];
    const int*   q_rel  = (const int*)  d_in[1];
    const int*   edges  = (const int*)  d_in[2];
    const float* rela   = (const float*)d_in[3];
    const float* Ws     = (const float*)d_in[4];
    const float* Wr     = (const float*)d_in[5];
    const float* Wqr    = (const float*)d_in[6];
    const float* Wqr_b  = (const float*)d_in[7];
    const float* Wattn  = (const float*)d_in[8];
    const float* Wh     = (const float*)d_in[9];
    float* out = (float*)d_out;

    // ---- workspace layout ----
    float* qr_pre  = (float*)d_ws;               // NB*64
    float* rel_pre = qr_pre + NB * DIM;          // NVOCAB*64
    float* hsWs    = rel_pre + NVOCAB * DIM;     // N_NODE*64
    size_t float_need = (size_t)(NB + NVOCAB + N_NODE) * DIM * sizeof(float);
    int* deg     = (int*)((char*)d_ws + float_need);  // N_NODE
    int* cursor  = deg + N_NODE;                      // N_NODE
    int* offs    = cursor + N_NODE;                   // N_NODE+1
    int* partial = offs + (N_NODE + 1);               // pad to 128
    int* csr_raw = partial + 128;
    int2* csr2   = (int2*)(((uintptr_t)csr_raw + 7) & ~(uintptr_t)7);
    size_t csr_need = ((char*)csr2 - (char*)d_ws) + (size_t)(N_EDGE + 1) * sizeof(int2);

    bool use_hw  = ws_size >= float_need;
    bool use_csr = ws_size >= csr_need;

    // ---- precompute tables (MFMA split-bf16 matvecs) ----
    gemm64_kernel<<<(NB + 15) / 16, 256, 0, stream>>>(rela, q_rel, Wqr, Wqr_b, qr_pre, NB, 0);
    gemm64_kernel<<<(NVOCAB + 15) / 16, 256, 0, stream>>>(rela, nullptr, Wr, nullptr, rel_pre, NVOCAB, 0);
    if (use_hw)
        gemm64_kernel<<<(N_NODE + 15) / 16, 256, 0, stream>>>(hidden, nullptr, Ws, nullptr, hsWs, N_NODE, 0);

    if (use_csr) {
        hipMemsetAsync(deg, 0, 2 * N_NODE * sizeof(int), stream);   // deg + cursor
        deg_kernel<<<(N_EDGE + 255) / 256, 256, 0, stream>>>(edges, deg);
        scan1_kernel<<<NCHUNK, SCAN_B, 0, stream>>>(deg, partial);
        scan2_kernel<<<1, 1, 0, stream>>>(partial, NCHUNK);
        scan3_kernel<<<NCHUNK, SCAN_B, 0, stream>>>(deg, partial, offs);
        scatter_kernel<<<(N_EDGE + 255) / 256, 256, 0, stream>>>(edges, offs, cursor, csr2);
        agg_kernel<<<(N_NODE * 64 + 255) / 256, 256, 0, stream>>>(
            csr2, offs, hidden, rela, hsWs, rel_pre, qr_pre, Wattn, out);
    } else {
        hipMemsetAsync(d_out, 0, (size_t)N_NODE * DIM * sizeof(float), stream);
        edge_kernel<<<(N_EDGE + 3) / 4, 256, 0, stream>>>(
            edges, hidden, rela, hsWs, rel_pre, qr_pre, Wattn, out);
    }

    // ---- out = relu(agg @ Wh^T), in-place, ~fp32 precision ----
    gemm64_kernel<<<(N_NODE + 15) / 16, 256, 0, stream>>>(out, nullptr, Wh, nullptr, out, N_NODE, 1);
}

// Round 5
// 343.497 us; speedup vs baseline: 1.9828x; 1.0618x over previous
//
#include <hip/hip_runtime.h>
#include <math.h>
#include <stdint.h>

#define N_NODE 100000
#define N_EDGE 1000000
#define DIM    64
#define NB     256
#define NVOCAB 401
#define SCAN_B 1024
#define NCHUNK ((N_NODE + SCAN_B - 1) / SCAN_B)
#define AGG_WAVES 8192   // ~ resident-wave capacity (256 CU x 32)

typedef short short8  __attribute__((ext_vector_type(8)));
typedef float floatx4 __attribute__((ext_vector_type(4)));

__device__ inline unsigned short f2bf_rne(float f)
{
    unsigned u = __float_as_uint(f);
    unsigned r = u + 0x7FFF + ((u >> 16) & 1);
    return (unsigned short)(r >> 16);
}

// ---------------------------------------------------------------------------
// gemm64: Y[r][:] = act( X[idx?idx[r]:r] @ W^T + bias ), W 64x64 row-major.
// MFMA 16x16x32 bf16 split-bf16 (hi/lo, 3 MFMA) => ~fp32 precision.
// Block = 4 waves; 16 rows x 64 cols (wave w -> cols 16w..16w+15).
// out_mode: 0 = fp32, 1 = fp32+relu, 2 = bf16 (no relu).
// In-place safe: all operand loads complete before __syncthreads(); stores after.
// ---------------------------------------------------------------------------
__device__ inline void split8(float4 v0, float4 v1, short8& hi, short8& lo)
{
    float f[8] = {v0.x, v0.y, v0.z, v0.w, v1.x, v1.y, v1.z, v1.w};
    #pragma unroll
    for (int j = 0; j < 8; ++j) {
        unsigned u = __float_as_uint(f[j]);
        unsigned r = u + 0x7FFF + ((u >> 16) & 1);      // RNE to bf16
        unsigned short h = (unsigned short)(r >> 16);
        float hf = __uint_as_float(((unsigned)h) << 16);
        float l  = f[j] - hf;
        unsigned u2 = __float_as_uint(l);
        unsigned r2 = u2 + 0x7FFF + ((u2 >> 16) & 1);
        hi[j] = (short)h;
        lo[j] = (short)(r2 >> 16);
    }
}

__global__ __launch_bounds__(256) void gemm64_kernel(
    const float* __restrict__ X,
    const int*   __restrict__ idx,
    const float* __restrict__ W,
    const float* __restrict__ bias,
    void* __restrict__ Yv,
    int R, int out_mode)
{
    int wave = threadIdx.x >> 6;
    int lane = threadIdx.x & 63;
    int m    = lane & 15;
    int quad = lane >> 4;
    int r0   = blockIdx.x * 16;
    int n0   = wave * 16;

    int r = r0 + m;
    int src = (r < R) ? (idx ? idx[r] : r) : 0;

    const float* xrow = X + (size_t)src * DIM + quad * 8;
    const float* wrow = W + (size_t)(n0 + m) * DIM + quad * 8;   // B col n0+m

    float4 a[2][2], b[2][2];
    #pragma unroll
    for (int c = 0; c < 2; ++c) {
        a[c][0] = *(const float4*)(xrow + 32 * c);
        a[c][1] = *(const float4*)(xrow + 32 * c + 4);
        b[c][0] = *(const float4*)(wrow + 32 * c);
        b[c][1] = *(const float4*)(wrow + 32 * c + 4);
    }
    float bv = bias ? bias[n0 + m] : 0.0f;
    __syncthreads();   // in-place safety: all X reads done before any Y store

    floatx4 acc = {0.f, 0.f, 0.f, 0.f};
    #pragma unroll
    for (int c = 0; c < 2; ++c) {
        short8 ah, al, bh, bl;
        split8(a[c][0], a[c][1], ah, al);
        split8(b[c][0], b[c][1], bh, bl);
        acc = __builtin_amdgcn_mfma_f32_16x16x32_bf16(ah, bh, acc, 0, 0, 0);
        acc = __builtin_amdgcn_mfma_f32_16x16x32_bf16(ah, bl, acc, 0, 0, 0);
        acc = __builtin_amdgcn_mfma_f32_16x16x32_bf16(al, bh, acc, 0, 0, 0);
    }

    #pragma unroll
    for (int g = 0; g < 4; ++g) {
        int rr = r0 + quad * 4 + g;             // D row = quad*4+reg, col = n0+m
        if (rr < R) {
            float v = acc[g] + bv;
            if (out_mode == 1) v = fmaxf(v, 0.0f);
            if (out_mode == 2)
                ((unsigned short*)Yv)[(size_t)rr * DIM + n0 + m] = f2bf_rne(v);
            else
                ((float*)Yv)[(size_t)rr * DIM + n0 + m] = v;
        }
    }
}

// fp32 -> bf16 bulk convert (float4 in, 4x bf16 out)
__global__ __launch_bounds__(256) void tobf16_kernel(const float* __restrict__ src,
                                                     unsigned short* __restrict__ dst,
                                                     int n4)
{
    int i = blockIdx.x * blockDim.x + threadIdx.x;
    if (i < n4) {
        float4 v = ((const float4*)src)[i];
        uint2 o;
        o.x = (unsigned)f2bf_rne(v.x) | ((unsigned)f2bf_rne(v.y) << 16);
        o.y = (unsigned)f2bf_rne(v.z) | ((unsigned)f2bf_rne(v.w) << 16);
        ((uint2*)dst)[i] = o;
    }
}

// ---------------------------------------------------------------------------
// CSR build
// ---------------------------------------------------------------------------
__global__ __launch_bounds__(256) void deg_kernel(const int* __restrict__ edges,
                                                  int* __restrict__ deg)
{
    int e = blockIdx.x * blockDim.x + threadIdx.x;
    if (e < N_EDGE) {
        int2 so = *(const int2*)(edges + (size_t)e * 6 + 4);
        atomicAdd(&deg[so.y], 1);
    }
}

__global__ __launch_bounds__(SCAN_B) void scan1_kernel(const int* __restrict__ deg,
                                                       int* __restrict__ partial)
{
    __shared__ int s[SCAN_B];
    int g = blockIdx.x * SCAN_B + threadIdx.x;
    s[threadIdx.x] = (g < N_NODE) ? deg[g] : 0;
    __syncthreads();
    for (int off = SCAN_B / 2; off; off >>= 1) {
        if (threadIdx.x < off) s[threadIdx.x] += s[threadIdx.x + off];
        __syncthreads();
    }
    if (threadIdx.x == 0) partial[blockIdx.x] = s[0];
}

// parallel exclusive scan of NCHUNK(=98) partials, one 128-thread block
// (R4 used a single-THREAD kernel: 98 serial dependent global RTs ~= 20-40us)
__global__ __launch_bounds__(128) void scan2_kernel(int* __restrict__ partial, int n)
{
    __shared__ int s[128];
    int t = threadIdx.x;
    int v = (t < n) ? partial[t] : 0;
    s[t] = v;
    __syncthreads();
    for (int off = 1; off < 128; off <<= 1) {
        int add = (t >= off) ? s[t - off] : 0;
        __syncthreads();
        s[t] += add;
        __syncthreads();
    }
    if (t < n) partial[t] = s[t] - v;   // exclusive
}

__global__ __launch_bounds__(SCAN_B) void scan3_kernel(const int* __restrict__ deg,
                                                       const int* __restrict__ partial,
                                                       int* __restrict__ offs)
{
    __shared__ int s[SCAN_B];
    int g = blockIdx.x * SCAN_B + threadIdx.x;
    s[threadIdx.x] = (g < N_NODE) ? deg[g] : 0;
    __syncthreads();
    for (int off = 1; off < SCAN_B; off <<= 1) {
        int add = ((int)threadIdx.x >= off) ? s[threadIdx.x - off] : 0;
        __syncthreads();
        s[threadIdx.x] += add;
        __syncthreads();
    }
    if (g < N_NODE) {
        offs[g + 1] = partial[blockIdx.x] + s[threadIdx.x];
        if (g == 0) offs[0] = 0;
    }
}

// scatter: csr2[slot] = (sub, rel<<8 | r_idx). Threads 0..3 write the 4 pad
// slots (agg reads up to csr2[i+q], i<=N_EDGE, q<=3; d_ws is 0xAA-poisoned).
__global__ __launch_bounds__(256) void scatter_kernel(const int* __restrict__ edges,
                                                      const int* __restrict__ offs,
                                                      int* __restrict__ cursor,
                                                      int2* __restrict__ csr2)
{
    int e = blockIdx.x * blockDim.x + threadIdx.x;
    if (e < 4) csr2[N_EDGE + e] = make_int2(0, 0);
    if (e < N_EDGE) {
        int2 ab = *(const int2*)(edges + (size_t)e * 6);      // (r_idx, 0)
        int2 cd = *(const int2*)(edges + (size_t)e * 6 + 2);  // (rel, 0)
        int2 ef = *(const int2*)(edges + (size_t)e * 6 + 4);  // (sub, obj)
        int slot = offs[ef.y] + atomicAdd(&cursor[ef.y], 1);
        csr2[slot] = make_int2(ef.x, (cd.x << 8) | ab.x);
    }
}

// ---------------------------------------------------------------------------
// Aggregation v3: persistent waves, 4 edges/iter (quarter-wave), bf16 gather
// tables, csr2 software prefetch (1-iter lookahead kills one RT per iter).
// lane = (quarter q = edge i+q, l = feature group: features 4l..4l+3).
// ---------------------------------------------------------------------------
__global__ __launch_bounds__(256) void agg_kernel(
    const int2*  __restrict__ csr2,          // [N_EDGE+4]
    const int*   __restrict__ offs,
    const unsigned short* __restrict__ hW,   // hsWs  bf16 [N_NODE][64]
    const unsigned short* __restrict__ hB,   // hidden bf16 [N_NODE][64]
    const float* __restrict__ rel_pre,       // fp32, L2-hot
    const float* __restrict__ qr_pre,
    const float* __restrict__ rela,
    const float* __restrict__ wattn,
    float* __restrict__ out)
{
    int lane = threadIdx.x & 63;
    int q    = lane >> 4;
    int l    = lane & 15;
    int f0   = l * 4;
    int wv = __builtin_amdgcn_readfirstlane((blockIdx.x * blockDim.x + threadIdx.x) >> 6);
    float4 wat = *(const float4*)(wattn + f0);

    for (int n = wv; n < N_NODE; n += AGG_WAVES) {
        int i   = offs[n];
        int end = offs[n + 1];
        float4 acc = make_float4(0.f, 0.f, 0.f, 0.f);

        int2 e = csr2[min(i + q, N_EDGE + 3)];   // prologue (pads cover i>=end)
        while (i < end) {
            int2 en = csr2[min(i + 4 + q, N_EDGE + 3)];   // prefetch next iter
            float valid = (i + q < end) ? 1.0f : 0.0f;
            int sub = e.x;
            int rl  = e.y >> 8;
            int ri  = e.y & 255;

            uint2  up = *(const uint2*)(hW + (size_t)sub * DIM + f0);
            uint2  uh = *(const uint2*)(hB + (size_t)sub * DIM + f0);
            float4 p2 = *(const float4*)(rel_pre + (size_t)rl * DIM + f0);
            float4 p3 = *(const float4*)(qr_pre  + (size_t)ri * DIM + f0);
            float4 rv = *(const float4*)(rela    + (size_t)rl * DIM + f0);

            float pw0 = __uint_as_float(up.x << 16);
            float pw1 = __uint_as_float(up.x & 0xFFFF0000u);
            float pw2 = __uint_as_float(up.y << 16);
            float pw3 = __uint_as_float(up.y & 0xFFFF0000u);

            float t =  fmaxf(pw0 + p2.x + p3.x, 0.f) * wat.x;
            t = fmaf(fmaxf(pw1 + p2.y + p3.y, 0.f), wat.y, t);
            t = fmaf(fmaxf(pw2 + p2.z + p3.z, 0.f), wat.z, t);
            t = fmaf(fmaxf(pw3 + p2.w + p3.w, 0.f), wat.w, t);
            t += __shfl_xor(t, 1);
            t += __shfl_xor(t, 2);
            t += __shfl_xor(t, 4);
            t += __shfl_xor(t, 8);               // reduce within quarter
            float alpha = valid / (1.0f + __expf(-t));

            float h0 = __uint_as_float(uh.x << 16);
            float h1 = __uint_as_float(uh.x & 0xFFFF0000u);
            float h2 = __uint_as_float(uh.y << 16);
            float h3 = __uint_as_float(uh.y & 0xFFFF0000u);

            // hyperbolic maps are identity to O(c)=1e-6 at c=1e-6
            acc.x = fmaf(alpha, h0 + rv.x, acc.x);
            acc.y = fmaf(alpha, h1 + rv.y, acc.y);
            acc.z = fmaf(alpha, h2 + rv.z, acc.z);
            acc.w = fmaf(alpha, h3 + rv.w, acc.w);

            e = en;
            i += 4;
        }

        // combine quarters (same feature group lives at lane l, l+16, l+32, l+48)
        acc.x += __shfl_xor(acc.x, 16); acc.x += __shfl_xor(acc.x, 32);
        acc.y += __shfl_xor(acc.y, 16); acc.y += __shfl_xor(acc.y, 32);
        acc.z += __shfl_xor(acc.z, 16); acc.z += __shfl_xor(acc.z, 32);
        acc.w += __shfl_xor(acc.w, 16); acc.w += __shfl_xor(acc.w, 32);
        if (q == 0)
            *(float4*)(out + (size_t)n * DIM + f0) = acc;
    }
}

// ---------------------------------------------------------------------------
// Fallback: atomic per-edge kernel (only if d_ws too small for CSR)
// ---------------------------------------------------------------------------
__global__ __launch_bounds__(256) void edge_kernel(
    const int*   __restrict__ edges,
    const float* __restrict__ hidden,
    const float* __restrict__ rela,
    const unsigned short* __restrict__ hW,
    const float* __restrict__ rel_pre,
    const float* __restrict__ qr_pre,
    const float* __restrict__ wattn,
    float* __restrict__ out)
{
    int e = (blockIdx.x * blockDim.x + threadIdx.x) >> 6;
    if (e >= N_EDGE) return;
    int lane = threadIdx.x & 63;
    int r_i = edges[e * 6 + 0];
    int rl  = edges[e * 6 + 2];
    int sb  = edges[e * 6 + 4];
    int ob  = edges[e * 6 + 5];
    float hs = hidden[(size_t)sb * DIM + lane];
    float hr = rela[(size_t)rl * DIM + lane];
    float p1 = __uint_as_float(((unsigned)hW[(size_t)sb * DIM + lane]) << 16);
    float pre = p1 + rel_pre[rl * DIM + lane] + qr_pre[r_i * DIM + lane];
    float t = wattn[lane] * fmaxf(pre, 0.0f);
    #pragma unroll
    for (int off = 32; off; off >>= 1) t += __shfl_xor(t, off);
    float alpha = 1.0f / (1.0f + __expf(-t));
    atomicAdd(&out[(size_t)ob * DIM + lane], (hs + hr) * alpha);
}

extern "C" void kernel_launch(void* const* d_in, const int* in_sizes, int n_in,
                              void* d_out, int out_size, void* d_ws, size_t ws_size,
                              hipStream_t stream)
{
    const float* hidden = (const float*)d_in[0];
    const int*   q_rel  = (const int*)  d_in[1];
    const int*   edges  = (const int*)  d_in[2];
    const float* rela   = (const float*)d_in[3];
    const float* Ws     = (const float*)d_in[4];
    const float* Wr     = (const float*)d_in[5];
    const float* Wqr    = (const float*)d_in[6];
    const float* Wqr_b  = (const float*)d_in[7];
    const float* Wattn  = (const float*)d_in[8];
    const float* Wh     = (const float*)d_in[9];
    float* out = (float*)d_out;

    // ---- workspace layout ----
    float* qr_pre  = (float*)d_ws;                       // NB*64 fp32
    float* rel_pre = qr_pre + NB * DIM;                  // NVOCAB*64 fp32
    unsigned short* hsWs = (unsigned short*)(rel_pre + NVOCAB * DIM);  // bf16
    unsigned short* hidb = hsWs + (size_t)N_NODE * DIM;                // bf16
    int* deg     = (int*)(hidb + (size_t)N_NODE * DIM);
    int* cursor  = deg + N_NODE;
    int* offs    = cursor + N_NODE;                      // N_NODE+1
    int* partial = offs + (N_NODE + 1);                  // 128 slots
    int* csr_raw = partial + 128;
    int2* csr2   = (int2*)(((uintptr_t)csr_raw + 7) & ~(uintptr_t)7);
    size_t csr_need = ((char*)csr2 - (char*)d_ws) + (size_t)(N_EDGE + 4) * sizeof(int2);
    size_t hw_need  = (size_t)((char*)deg - (char*)d_ws);

    bool use_hw  = ws_size >= hw_need;
    bool use_csr = ws_size >= csr_need;
    (void)use_hw;

    // ---- precompute tables ----
    tobf16_kernel<<<(N_NODE * 16 + 255) / 256, 256, 0, stream>>>(hidden, hidb, N_NODE * 16);
    gemm64_kernel<<<(NB + 15) / 16, 256, 0, stream>>>(rela, q_rel, Wqr, Wqr_b, qr_pre, NB, 0);
    gemm64_kernel<<<(NVOCAB + 15) / 16, 256, 0, stream>>>(rela, nullptr, Wr, nullptr, rel_pre, NVOCAB, 0);
    gemm64_kernel<<<(N_NODE + 15) / 16, 256, 0, stream>>>(hidden, nullptr, Ws, nullptr, hsWs, N_NODE, 2);

    if (use_csr) {
        hipMemsetAsync(deg, 0, 2 * N_NODE * sizeof(int), stream);   // deg + cursor
        deg_kernel<<<(N_EDGE + 255) / 256, 256, 0, stream>>>(edges, deg);
        scan1_kernel<<<NCHUNK, SCAN_B, 0, stream>>>(deg, partial);
        scan2_kernel<<<1, 128, 0, stream>>>(partial, NCHUNK);
        scan3_kernel<<<NCHUNK, SCAN_B, 0, stream>>>(deg, partial, offs);
        scatter_kernel<<<(N_EDGE + 255) / 256, 256, 0, stream>>>(edges, offs, cursor, csr2);
        agg_kernel<<<AGG_WAVES / 4, 256, 0, stream>>>(
            csr2, offs, hsWs, hidb, rel_pre, qr_pre, rela, Wattn, out);
    } else {
        hipMemsetAsync(d_out, 0, (size_t)N_NODE * DIM * sizeof(float), stream);
        edge_kernel<<<(N_EDGE + 3) / 4, 256, 0, stream>>>(
            edges, hidden, rela, hsWs, rel_pre, qr_pre, Wattn, out);
    }

    // ---- out = relu(agg @ Wh^T), in-place ----
    gemm64_kernel<<<(N_NODE + 15) / 16, 256, 0, stream>>>(out, nullptr, Wh, nullptr, out, N_NODE, 1);
}

// Round 7
// 338.170 us; speedup vs baseline: 2.0140x; 1.0158x over previous
//
#include <hip/hip_runtime.h>
#include <math.h>
#include <stdint.h>

#define N_NODE 100000
#define N_EDGE 1000000
#define DIM    64
#define NB     256
#define NVOCAB 401
#define SCAN_B 1024
#define NCHUNK ((N_NODE + SCAN_B - 1) / SCAN_B)
#define AGG_WAVES 8192

typedef short short8  __attribute__((ext_vector_type(8)));
typedef float floatx4 __attribute__((ext_vector_type(4)));
typedef unsigned short ushort_t;

__device__ inline unsigned short f2bf_rne(float f)
{
    unsigned u = __float_as_uint(f);
    unsigned r = u + 0x7FFF + ((u >> 16) & 1);
    return (unsigned short)(r >> 16);
}
__device__ inline float bflo(unsigned u) { return __uint_as_float(u << 16); }
__device__ inline float bfhi(unsigned u) { return __uint_as_float(u & 0xFFFF0000u); }
__device__ inline unsigned short f2h(float f)
{
    _Float16 h = (_Float16)f;
    unsigned short s; __builtin_memcpy(&s, &h, 2); return s;
}
__device__ inline float h2f(unsigned b)
{
    unsigned short s = (unsigned short)b;
    _Float16 h; __builtin_memcpy(&h, &s, 2); return (float)h;
}

// ---------------------------------------------------------------------------
// gemm64 v2: Y[r][:] = act( X[idx?idx[r]:r] @ W^T + bias ), W 64x64 row-major.
// Split-bf16 (hi/lo) 3-MFMA => ~fp32 precision. Block = 4 waves = 64 rows;
// wave w owns rows r0+16w..+15 and computes ALL 64 cols (X read exactly once).
// In-place safe per-wave (each wave reads only the rows it writes; its loads
// complete before its stores). out_mode: 0 fp32 | 1 fp32+relu | 2 bf16 |
// 3 bf16 + also store bf16(X rows) to Y2 (free from the loaded A frags).
// ---------------------------------------------------------------------------
__device__ inline void split8(float4 v0, float4 v1, short8& hi, short8& lo)
{
    float f[8] = {v0.x, v0.y, v0.z, v0.w, v1.x, v1.y, v1.z, v1.w};
    #pragma unroll
    for (int j = 0; j < 8; ++j) {
        unsigned u = __float_as_uint(f[j]);
        unsigned r = u + 0x7FFF + ((u >> 16) & 1);
        unsigned short h = (unsigned short)(r >> 16);
        float hf = __uint_as_float(((unsigned)h) << 16);
        float l  = f[j] - hf;
        unsigned u2 = __float_as_uint(l);
        unsigned r2 = u2 + 0x7FFF + ((u2 >> 16) & 1);
        hi[j] = (short)h;
        lo[j] = (short)(r2 >> 16);
    }
}

__global__ __launch_bounds__(256) void gemm64_kernel(
    const float* __restrict__ X,
    const int*   __restrict__ idx,
    const float* __restrict__ W,
    const float* __restrict__ bias,
    void* __restrict__ Yv,
    ushort_t* __restrict__ Y2,
    int R, int out_mode)
{
    int wave = threadIdx.x >> 6;
    int lane = threadIdx.x & 63;
    int m    = lane & 15;
    int quad = lane >> 4;
    int r0   = blockIdx.x * 64 + wave * 16;

    int r = r0 + m;
    int src = (r < R) ? (idx ? idx[r] : r) : 0;
    const float* xrow = X + (size_t)src * DIM + quad * 8;

    float4 a0[2], a1[2];
    #pragma unroll
    for (int c = 0; c < 2; ++c) {
        a0[c] = *(const float4*)(xrow + 32 * c);
        a1[c] = *(const float4*)(xrow + 32 * c + 4);
    }
    short8 ah[2], al[2];
    #pragma unroll
    for (int c = 0; c < 2; ++c) split8(a0[c], a1[c], ah[c], al[c]);

    if (out_mode == 3 && r < R) {   // bf16 copy of X rows, free from A frags
        #pragma unroll
        for (int c = 0; c < 2; ++c)
            *(short8*)(Y2 + (size_t)r * DIM + 32 * c + quad * 8) = ah[c];
    }

    floatx4 acc[4] = {{0,0,0,0},{0,0,0,0},{0,0,0,0},{0,0,0,0}};
    #pragma unroll
    for (int g = 0; g < 4; ++g) {
        const float* wrow = W + (size_t)(g * 16 + m) * DIM + quad * 8;
        #pragma unroll
        for (int c = 0; c < 2; ++c) {
            float4 b0 = *(const float4*)(wrow + 32 * c);
            float4 b1 = *(const float4*)(wrow + 32 * c + 4);
            short8 bh, bl;
            split8(b0, b1, bh, bl);
            acc[g] = __builtin_amdgcn_mfma_f32_16x16x32_bf16(ah[c], bh, acc[g], 0, 0, 0);
            acc[g] = __builtin_amdgcn_mfma_f32_16x16x32_bf16(ah[c], bl, acc[g], 0, 0, 0);
            acc[g] = __builtin_amdgcn_mfma_f32_16x16x32_bf16(al[c], bh, acc[g], 0, 0, 0);
        }
    }

    #pragma unroll
    for (int g = 0; g < 4; ++g) {
        float bv = bias ? bias[g * 16 + m] : 0.0f;
        #pragma unroll
        for (int reg = 0; reg < 4; ++reg) {
            int rr = r0 + quad * 4 + reg;        // D row = quad*4+reg (own rows)
            if (rr < R) {
                float v = acc[g][reg] + bv;      // D col = g*16 + (lane&15)
                if (out_mode == 1) v = fmaxf(v, 0.0f);
                if (out_mode >= 2)
                    ((ushort_t*)Yv)[(size_t)rr * DIM + g * 16 + m] = f2bf_rne(v);
                else
                    ((float*)Yv)[(size_t)rr * DIM + g * 16 + m] = v;
            }
        }
    }
}

// ---------------------------------------------------------------------------
// alpha + degree, fused single pass over edges. Quarter-wave: 16 lanes/edge,
// 4 edges/wave => 16 edges/block. Streaming, no loop-carried deps.
// ---------------------------------------------------------------------------
__global__ __launch_bounds__(256) void alpha_deg_kernel(
    const int*      __restrict__ edges,
    const ushort_t* __restrict__ hsWs,      // bf16 [N_NODE][64]
    const ushort_t* __restrict__ rel_preb,  // bf16 [NVOCAB][64]
    const ushort_t* __restrict__ qr_preb,   // bf16 [NB][64]
    const float*    __restrict__ wattn,
    ushort_t*       __restrict__ alpha16,
    int*            __restrict__ deg)
{
    int gid  = blockIdx.x * 256 + threadIdx.x;
    int lane = threadIdx.x & 63;
    int q    = lane >> 4;
    int l    = lane & 15;
    int e    = (gid >> 6) * 4 + q;          // wave id * 4 + quarter
    if (e >= N_EDGE) return;

    int2 ab = *(const int2*)(edges + (size_t)e * 6);      // r_idx
    int2 cd = *(const int2*)(edges + (size_t)e * 6 + 2);  // rel
    int2 ef = *(const int2*)(edges + (size_t)e * 6 + 4);  // sub, obj
    if (l == 0) atomicAdd(&deg[ef.y], 1);

    int f0 = l * 4;
    uint2 uh = *(const uint2*)(hsWs     + (size_t)ef.x * DIM + f0);
    uint2 ur = *(const uint2*)(rel_preb + (size_t)cd.x * DIM + f0);
    uint2 uq = *(const uint2*)(qr_preb  + (size_t)ab.x * DIM + f0);
    float4 wa = *(const float4*)(wattn + f0);

    float t =  fmaxf(bflo(uh.x) + bflo(ur.x) + bflo(uq.x), 0.f) * wa.x;
    t = fmaf(fmaxf(bfhi(uh.x) + bfhi(ur.x) + bfhi(uq.x), 0.f), wa.y, t);
    t = fmaf(fmaxf(bflo(uh.y) + bflo(ur.y) + bflo(uq.y), 0.f), wa.z, t);
    t = fmaf(fmaxf(bfhi(uh.y) + bfhi(ur.y) + bfhi(uq.y), 0.f), wa.w, t);
    t += __shfl_xor(t, 1);
    t += __shfl_xor(t, 2);
    t += __shfl_xor(t, 4);
    t += __shfl_xor(t, 8);

    if (l == 0) alpha16[e] = f2h(1.0f / (1.0f + __expf(-t)));
}

// ---------------------------------------------------------------------------
// CSR build
// ---------------------------------------------------------------------------
__global__ __launch_bounds__(SCAN_B) void scan1_kernel(const int* __restrict__ deg,
                                                       int* __restrict__ partial)
{
    __shared__ int s[SCAN_B];
    int g = blockIdx.x * SCAN_B + threadIdx.x;
    s[threadIdx.x] = (g < N_NODE) ? deg[g] : 0;
    __syncthreads();
    for (int off = SCAN_B / 2; off; off >>= 1) {
        if (threadIdx.x < off) s[threadIdx.x] += s[threadIdx.x + off];
        __syncthreads();
    }
    if (threadIdx.x == 0) partial[blockIdx.x] = s[0];
}

__global__ __launch_bounds__(128) void scan2_kernel(int* __restrict__ partial, int n)
{
    __shared__ int s[128];
    int t = threadIdx.x;
    int v = (t < n) ? partial[t] : 0;
    s[t] = v;
    __syncthreads();
    for (int off = 1; off < 128; off <<= 1) {
        int add = (t >= off) ? s[t - off] : 0;
        __syncthreads();
        s[t] += add;
        __syncthreads();
    }
    if (t < n) partial[t] = s[t] - v;   // exclusive
}

__global__ __launch_bounds__(SCAN_B) void scan3_kernel(const int* __restrict__ deg,
                                                       const int* __restrict__ partial,
                                                       int* __restrict__ offs)
{
    __shared__ int s[SCAN_B];
    int g = blockIdx.x * SCAN_B + threadIdx.x;
    s[threadIdx.x] = (g < N_NODE) ? deg[g] : 0;
    __syncthreads();
    for (int off = 1; off < SCAN_B; off <<= 1) {
        int add = ((int)threadIdx.x >= off) ? s[threadIdx.x - off] : 0;
        __syncthreads();
        s[threadIdx.x] += add;
        __syncthreads();
    }
    if (g < N_NODE) {
        offs[g + 1] = partial[blockIdx.x] + s[threadIdx.x];
        if (g == 0) offs[0] = 0;
    }
}

// scatter: csr2[slot] = (sub, rel<<16 | alpha_f16bits). rel<=400 needs 9 bits.
// Threads 0..3 rewrite the 4 pad slots every call (d_ws is 0xAA-poisoned).
__global__ __launch_bounds__(256) void scatter_kernel(const int* __restrict__ edges,
                                                      const ushort_t* __restrict__ alpha16,
                                                      const int* __restrict__ offs,
                                                      int* __restrict__ cursor,
                                                      int2* __restrict__ csr2)
{
    int e = blockIdx.x * blockDim.x + threadIdx.x;
    if (e < 4) csr2[N_EDGE + e] = make_int2(0, 0);
    if (e < N_EDGE) {
        int2 cd = *(const int2*)(edges + (size_t)e * 6 + 2);  // rel
        int2 ef = *(const int2*)(edges + (size_t)e * 6 + 4);  // sub, obj
        unsigned a = alpha16[e];
        int slot = offs[ef.y] + atomicAdd(&cursor[ef.y], 1);
        csr2[slot] = make_int2(ef.x, (int)(((unsigned)cd.x << 16) | a));
    }
}

// ---------------------------------------------------------------------------
// Aggregation v4: persistent waves, 4 edges/iter, alpha precomputed -> no
// shuffle/sigmoid in loop. Per iter: prefetched 8B csr2 + 2 bf16 gathers + FMA.
// ---------------------------------------------------------------------------
__global__ __launch_bounds__(256) void agg_kernel(
    const int2*     __restrict__ csr2,   // [N_EDGE+4]
    const int*      __restrict__ offs,
    const ushort_t* __restrict__ hB,     // hidden bf16 [N_NODE][64]
    const ushort_t* __restrict__ relab,  // rela  bf16 [NVOCAB][64], L2-hot
    float* __restrict__ out)
{
    int lane = threadIdx.x & 63;
    int q    = lane >> 4;
    int l    = lane & 15;
    int f0   = l * 4;
    int wv = __builtin_amdgcn_readfirstlane((blockIdx.x * blockDim.x + threadIdx.x) >> 6);

    for (int n = wv; n < N_NODE; n += AGG_WAVES) {
        int i   = offs[n];
        int end = offs[n + 1];
        float4 acc = make_float4(0.f, 0.f, 0.f, 0.f);

        int2 e = csr2[min(i + q, N_EDGE + 3)];
        while (i < end) {
            int2 en = csr2[min(i + 4 + q, N_EDGE + 3)];
            float valid = (i + q < end) ? 1.0f : 0.0f;
            int sub = e.x;
            unsigned ey = (unsigned)e.y;
            float alpha = valid * h2f(ey & 0xFFFFu);
            int rl = (int)(ey >> 16);

            uint2 uh = *(const uint2*)(hB    + (size_t)sub * DIM + f0);
            uint2 ur = *(const uint2*)(relab + (size_t)rl  * DIM + f0);

            acc.x = fmaf(alpha, bflo(uh.x) + bflo(ur.x), acc.x);
            acc.y = fmaf(alpha, bfhi(uh.x) + bfhi(ur.x), acc.y);
            acc.z = fmaf(alpha, bflo(uh.y) + bflo(ur.y), acc.z);
            acc.w = fmaf(alpha, bfhi(uh.y) + bfhi(ur.y), acc.w);

            e = en;
            i += 4;
        }

        acc.x += __shfl_xor(acc.x, 16); acc.x += __shfl_xor(acc.x, 32);
        acc.y += __shfl_xor(acc.y, 16); acc.y += __shfl_xor(acc.y, 32);
        acc.z += __shfl_xor(acc.z, 16); acc.z += __shfl_xor(acc.z, 32);
        acc.w += __shfl_xor(acc.w, 16); acc.w += __shfl_xor(acc.w, 32);
        if (q == 0)
            *(float4*)(out + (size_t)n * DIM + f0) = acc;
    }
}

// ---------------------------------------------------------------------------
// Fallback (ws too small for CSR): wave-per-edge atomic kernel, bf16 tables.
// ---------------------------------------------------------------------------
__global__ __launch_bounds__(256) void edge_kernel(
    const int*      __restrict__ edges,
    const ushort_t* __restrict__ hB,
    const ushort_t* __restrict__ relab,
    const ushort_t* __restrict__ hsWs,
    const ushort_t* __restrict__ rel_preb,
    const ushort_t* __restrict__ qr_preb,
    const float*    __restrict__ wattn,
    float* __restrict__ out)
{
    int e = (blockIdx.x * blockDim.x + threadIdx.x) >> 6;
    if (e >= N_EDGE) return;
    int lane = threadIdx.x & 63;
    int r_i = edges[e * 6 + 0];
    int rl  = edges[e * 6 + 2];
    int sb  = edges[e * 6 + 4];
    int ob  = edges[e * 6 + 5];
    float hs = __uint_as_float(((unsigned)hB[(size_t)sb * DIM + lane]) << 16);
    float hr = __uint_as_float(((unsigned)relab[(size_t)rl * DIM + lane]) << 16);
    float p1 = __uint_as_float(((unsigned)hsWs[(size_t)sb * DIM + lane]) << 16);
    float p2 = __uint_as_float(((unsigned)rel_preb[(size_t)rl * DIM + lane]) << 16);
    float p3 = __uint_as_float(((unsigned)qr_preb[(size_t)r_i * DIM + lane]) << 16);
    float t = wattn[lane] * fmaxf(p1 + p2 + p3, 0.0f);
    #pragma unroll
    for (int off = 32; off; off >>= 1) t += __shfl_xor(t, off);
    float alpha = 1.0f / (1.0f + __expf(-t));
    atomicAdd(&out[(size_t)ob * DIM + lane], (hs + hr) * alpha);
}

extern "C" void kernel_launch(void* const* d_in, const int* in_sizes, int n_in,
                              void* d_out, int out_size, void* d_ws, size_t ws_size,
                              hipStream_t stream)
{
    const float* hidden = (const float*)d_in[0];
    const int*   q_rel  = (const int*)  d_in[1];
    const int*   edges  = (const int*)  d_in[2];
    const float* rela   = (const float*)d_in[3];
    const float* Ws     = (const float*)d_in[4];
    const float* Wr     = (const float*)d_in[5];
    const float* Wqr    = (const float*)d_in[6];
    const float* Wqr_b  = (const float*)d_in[7];
    const float* Wattn  = (const float*)d_in[8];
    const float* Wh     = (const float*)d_in[9];
    float* out = (float*)d_out;

    // ---- workspace layout ----
    ushort_t* qr_preb  = (ushort_t*)d_ws;                 // 256*64 bf16
    ushort_t* rel_preb = qr_preb + NB * DIM;              // 401*64 bf16
    ushort_t* relab    = rel_preb + NVOCAB * DIM;         // 401*64 bf16
    ushort_t* hsWs     = relab + NVOCAB * DIM;            // 100000*64 bf16
    ushort_t* hidb     = hsWs + (size_t)N_NODE * DIM;     // 100000*64 bf16
    ushort_t* alpha16  = hidb + (size_t)N_NODE * DIM;     // N_EDGE fp16
    int* deg     = (int*)(alpha16 + N_EDGE);
    int* cursor  = deg + N_NODE;
    int* offs    = cursor + N_NODE;                       // N_NODE+1
    int* partial = offs + (N_NODE + 1);                   // 128 slots
    int* csr_raw = partial + 128;
    int2* csr2   = (int2*)(((uintptr_t)csr_raw + 7) & ~(uintptr_t)7);
    size_t csr_need = ((char*)csr2 - (char*)d_ws) + (size_t)(N_EDGE + 4) * sizeof(int2);
    bool use_csr = ws_size >= csr_need;

    // ---- precompute tables (out_mode 3 also emits bf16(X) for free) ----
    gemm64_kernel<<<(NVOCAB + 63) / 64, 256, 0, stream>>>(
        rela, nullptr, Wr, nullptr, rel_preb, relab, NVOCAB, 3);
    gemm64_kernel<<<(NB + 63) / 64, 256, 0, stream>>>(
        rela, q_rel, Wqr, Wqr_b, qr_preb, nullptr, NB, 2);
    gemm64_kernel<<<(N_NODE + 63) / 64, 256, 0, stream>>>(
        hidden, nullptr, Ws, nullptr, hsWs, hidb, N_NODE, 3);

    if (use_csr) {
        hipMemsetAsync(deg, 0, 2 * N_NODE * sizeof(int), stream);   // deg + cursor
        // 16 edges per block (4 waves x 4 edges)  [R6 bug: was /1024*4 -> 6% coverage]
        alpha_deg_kernel<<<(N_EDGE + 15) / 16, 256, 0, stream>>>(
            edges, hsWs, rel_preb, qr_preb, Wattn, alpha16, deg);
        scan1_kernel<<<NCHUNK, SCAN_B, 0, stream>>>(deg, partial);
        scan2_kernel<<<1, 128, 0, stream>>>(partial, NCHUNK);
        scan3_kernel<<<NCHUNK, SCAN_B, 0, stream>>>(deg, partial, offs);
        scatter_kernel<<<(N_EDGE + 255) / 256, 256, 0, stream>>>(
            edges, alpha16, offs, cursor, csr2);
        agg_kernel<<<AGG_WAVES / 4, 256, 0, stream>>>(csr2, offs, hidb, relab, out);
    } else {
        hipMemsetAsync(d_out, 0, (size_t)N_NODE * DIM * sizeof(float), stream);
        edge_kernel<<<(N_EDGE + 3) / 4, 256, 0, stream>>>(
            edges, hidb, relab, hsWs, rel_preb, qr_preb, Wattn, out);
    }

    // ---- out = relu(agg @ Wh^T), in-place ----
    gemm64_kernel<<<(N_NODE + 63) / 64, 256, 0, stream>>>(
        out, nullptr, Wh, nullptr, out, nullptr, N_NODE, 1);
}

// Round 8
// 300.141 us; speedup vs baseline: 2.2692x; 1.1267x over previous
//
#include <hip/hip_runtime.h>
#include <math.h>
#include <stdint.h>

#define N_NODE 100000
#define N_EDGE 1000000
#define DIM    64
#define NB     256
#define NVOCAB 401
#define SCAN_B 1024
#define NCHUNK ((N_NODE + SCAN_B - 1) / SCAN_B)
#define AGG_WAVES 8192

typedef short short8  __attribute__((ext_vector_type(8)));
typedef float floatx4 __attribute__((ext_vector_type(4)));
typedef unsigned short ushort_t;

__device__ inline unsigned short f2bf_rne(float f)
{
    unsigned u = __float_as_uint(f);
    unsigned r = u + 0x7FFF + ((u >> 16) & 1);
    return (unsigned short)(r >> 16);
}
__device__ inline float bflo(unsigned u) { return __uint_as_float(u << 16); }
__device__ inline float bfhi(unsigned u) { return __uint_as_float(u & 0xFFFF0000u); }
__device__ inline unsigned short f2h(float f)
{
    _Float16 h = (_Float16)f;
    unsigned short s; __builtin_memcpy(&s, &h, 2); return s;
}
__device__ inline float h2f(unsigned b)
{
    unsigned short s = (unsigned short)b;
    _Float16 h; __builtin_memcpy(&h, &s, 2); return (float)h;
}

// ---------------------------------------------------------------------------
// gemm64 v2: Y[r][:] = act( X[idx?idx[r]:r] @ W^T + bias ), W 64x64 row-major.
// Split-bf16 (hi/lo) 3-MFMA => ~fp32 precision. Block = 4 waves = 64 rows;
// wave w owns rows r0+16w..+15 and computes ALL 64 cols (X read exactly once).
// In-place safe per-wave. out_mode: 0 fp32 | 1 fp32+relu | 2 bf16 |
// 3 bf16 + also store bf16(X rows) to Y2 (free from the loaded A frags).
// ---------------------------------------------------------------------------
__device__ inline void split8(float4 v0, float4 v1, short8& hi, short8& lo)
{
    float f[8] = {v0.x, v0.y, v0.z, v0.w, v1.x, v1.y, v1.z, v1.w};
    #pragma unroll
    for (int j = 0; j < 8; ++j) {
        unsigned u = __float_as_uint(f[j]);
        unsigned r = u + 0x7FFF + ((u >> 16) & 1);
        unsigned short h = (unsigned short)(r >> 16);
        float hf = __uint_as_float(((unsigned)h) << 16);
        float l  = f[j] - hf;
        unsigned u2 = __float_as_uint(l);
        unsigned r2 = u2 + 0x7FFF + ((u2 >> 16) & 1);
        hi[j] = (short)h;
        lo[j] = (short)(r2 >> 16);
    }
}

__global__ __launch_bounds__(256) void gemm64_kernel(
    const float* __restrict__ X,
    const int*   __restrict__ idx,
    const float* __restrict__ W,
    const float* __restrict__ bias,
    void* __restrict__ Yv,
    ushort_t* __restrict__ Y2,
    int R, int out_mode)
{
    int wave = threadIdx.x >> 6;
    int lane = threadIdx.x & 63;
    int m    = lane & 15;
    int quad = lane >> 4;
    int r0   = blockIdx.x * 64 + wave * 16;

    int r = r0 + m;
    int src = (r < R) ? (idx ? idx[r] : r) : 0;
    const float* xrow = X + (size_t)src * DIM + quad * 8;

    float4 a0[2], a1[2];
    #pragma unroll
    for (int c = 0; c < 2; ++c) {
        a0[c] = *(const float4*)(xrow + 32 * c);
        a1[c] = *(const float4*)(xrow + 32 * c + 4);
    }
    short8 ah[2], al[2];
    #pragma unroll
    for (int c = 0; c < 2; ++c) split8(a0[c], a1[c], ah[c], al[c]);

    if (out_mode == 3 && r < R) {   // bf16 copy of X rows, free from A frags
        #pragma unroll
        for (int c = 0; c < 2; ++c)
            *(short8*)(Y2 + (size_t)r * DIM + 32 * c + quad * 8) = ah[c];
    }

    floatx4 acc[4] = {{0,0,0,0},{0,0,0,0},{0,0,0,0},{0,0,0,0}};
    #pragma unroll
    for (int g = 0; g < 4; ++g) {
        const float* wrow = W + (size_t)(g * 16 + m) * DIM + quad * 8;
        #pragma unroll
        for (int c = 0; c < 2; ++c) {
            float4 b0 = *(const float4*)(wrow + 32 * c);
            float4 b1 = *(const float4*)(wrow + 32 * c + 4);
            short8 bh, bl;
            split8(b0, b1, bh, bl);
            acc[g] = __builtin_amdgcn_mfma_f32_16x16x32_bf16(ah[c], bh, acc[g], 0, 0, 0);
            acc[g] = __builtin_amdgcn_mfma_f32_16x16x32_bf16(ah[c], bl, acc[g], 0, 0, 0);
            acc[g] = __builtin_amdgcn_mfma_f32_16x16x32_bf16(al[c], bh, acc[g], 0, 0, 0);
        }
    }

    #pragma unroll
    for (int g = 0; g < 4; ++g) {
        float bv = bias ? bias[g * 16 + m] : 0.0f;
        #pragma unroll
        for (int reg = 0; reg < 4; ++reg) {
            int rr = r0 + quad * 4 + reg;        // D row = quad*4+reg (own rows)
            if (rr < R) {
                float v = acc[g][reg] + bv;      // D col = g*16 + (lane&15)
                if (out_mode == 1) v = fmaxf(v, 0.0f);
                if (out_mode >= 2)
                    ((ushort_t*)Yv)[(size_t)rr * DIM + g * 16 + m] = f2bf_rne(v);
                else
                    ((float*)Yv)[(size_t)rr * DIM + g * 16 + m] = v;
            }
        }
    }
}

// ---------------------------------------------------------------------------
// deg + rank: isolates ALL edge atomics in one pass with nothing else to
// stall. rank[e] = arrival index of e within its obj node -> scatter slot is
// offs[obj]+rank[e] later, no cursor atomics needed.
// ---------------------------------------------------------------------------
__global__ __launch_bounds__(256) void deg_rank_kernel(const int* __restrict__ edges,
                                                       int* __restrict__ deg,
                                                       int* __restrict__ rank)
{
    int e = blockIdx.x * blockDim.x + threadIdx.x;
    if (e < N_EDGE) {
        int2 so = *(const int2*)(edges + (size_t)e * 6 + 4);  // (sub, obj)
        rank[e] = atomicAdd(&deg[so.y], 1);
    }
}

// ---------------------------------------------------------------------------
// CSR scan pipeline
// ---------------------------------------------------------------------------
__global__ __launch_bounds__(SCAN_B) void scan1_kernel(const int* __restrict__ deg,
                                                       int* __restrict__ partial)
{
    __shared__ int s[SCAN_B];
    int g = blockIdx.x * SCAN_B + threadIdx.x;
    s[threadIdx.x] = (g < N_NODE) ? deg[g] : 0;
    __syncthreads();
    for (int off = SCAN_B / 2; off; off >>= 1) {
        if (threadIdx.x < off) s[threadIdx.x] += s[threadIdx.x + off];
        __syncthreads();
    }
    if (threadIdx.x == 0) partial[blockIdx.x] = s[0];
}

__global__ __launch_bounds__(128) void scan2_kernel(int* __restrict__ partial, int n)
{
    __shared__ int s[128];
    int t = threadIdx.x;
    int v = (t < n) ? partial[t] : 0;
    s[t] = v;
    __syncthreads();
    for (int off = 1; off < 128; off <<= 1) {
        int add = (t >= off) ? s[t - off] : 0;
        __syncthreads();
        s[t] += add;
        __syncthreads();
    }
    if (t < n) partial[t] = s[t] - v;   // exclusive
}

__global__ __launch_bounds__(SCAN_B) void scan3_kernel(const int* __restrict__ deg,
                                                       const int* __restrict__ partial,
                                                       int* __restrict__ offs)
{
    __shared__ int s[SCAN_B];
    int g = blockIdx.x * SCAN_B + threadIdx.x;
    s[threadIdx.x] = (g < N_NODE) ? deg[g] : 0;
    __syncthreads();
    for (int off = 1; off < SCAN_B; off <<= 1) {
        int add = ((int)threadIdx.x >= off) ? s[threadIdx.x - off] : 0;
        __syncthreads();
        s[threadIdx.x] += add;
        __syncthreads();
    }
    if (g < N_NODE) {
        offs[g + 1] = partial[blockIdx.x] + s[threadIdx.x];
        if (g == 0) offs[0] = 0;
    }
}

// ---------------------------------------------------------------------------
// alpha + scatter, fused: one pass over edges. Quarter-wave (16 lanes/edge),
// 2 edges per quarter (independent chains -> 2x MLP), 8 edges/wave,
// 32 edges/block. Atomic-free: slot = offs[obj] + rank[e]. Writes csr2
// entry (sub, rel<<16|alpha_f16) directly. Threads 0..3 rewrite pad slots.
// ---------------------------------------------------------------------------
__global__ __launch_bounds__(256) void alpha_scatter_kernel(
    const int*      __restrict__ edges,
    const int*      __restrict__ rank,
    const int*      __restrict__ offs,
    const ushort_t* __restrict__ hsWs,      // bf16 [N_NODE][64]
    const ushort_t* __restrict__ rel_preb,  // bf16 [NVOCAB][64]
    const ushort_t* __restrict__ qr_preb,   // bf16 [NB][64]
    const float*    __restrict__ wattn,
    int2*           __restrict__ csr2)
{
    int tid = blockIdx.x * 256 + threadIdx.x;
    if (tid < 4) csr2[N_EDGE + tid] = make_int2(0, 0);

    int wave = threadIdx.x >> 6;
    int lane = threadIdx.x & 63;
    int q    = lane >> 4;
    int l    = lane & 15;
    int f0   = l * 4;
    int e0   = (blockIdx.x * 4 + wave) * 8 + q * 2;   // this quarter: e0, e0+1

    float4 wa = *(const float4*)(wattn + f0);

    int   sub[2], rl[2], ri[2], ob[2];
    float t[2];
    #pragma unroll
    for (int j = 0; j < 2; ++j) {
        int e = min(e0 + j, N_EDGE - 1);              // clamp; store guarded below
        int2 ab = *(const int2*)(edges + (size_t)e * 6);      // r_idx
        int2 cd = *(const int2*)(edges + (size_t)e * 6 + 2);  // rel
        int2 ef = *(const int2*)(edges + (size_t)e * 6 + 4);  // sub, obj
        ri[j] = ab.x; rl[j] = cd.x; sub[j] = ef.x; ob[j] = ef.y;

        uint2 uh = *(const uint2*)(hsWs     + (size_t)ef.x * DIM + f0);
        uint2 ur = *(const uint2*)(rel_preb + (size_t)cd.x * DIM + f0);
        uint2 uq = *(const uint2*)(qr_preb  + (size_t)ab.x * DIM + f0);

        float tt =  fmaxf(bflo(uh.x) + bflo(ur.x) + bflo(uq.x), 0.f) * wa.x;
        tt = fmaf(fmaxf(bfhi(uh.x) + bfhi(ur.x) + bfhi(uq.x), 0.f), wa.y, tt);
        tt = fmaf(fmaxf(bflo(uh.y) + bflo(ur.y) + bflo(uq.y), 0.f), wa.z, tt);
        tt = fmaf(fmaxf(bfhi(uh.y) + bfhi(ur.y) + bfhi(uq.y), 0.f), wa.w, tt);
        t[j] = tt;
    }
    #pragma unroll
    for (int j = 0; j < 2; ++j) {
        t[j] += __shfl_xor(t[j], 1);
        t[j] += __shfl_xor(t[j], 2);
        t[j] += __shfl_xor(t[j], 4);
        t[j] += __shfl_xor(t[j], 8);              // reduced within quarter
    }

    if (l == 0) {
        #pragma unroll
        for (int j = 0; j < 2; ++j) {
            int e = e0 + j;
            if (e < N_EDGE) {
                float alpha = 1.0f / (1.0f + __expf(-t[j]));
                int slot = offs[ob[j]] + rank[e];
                csr2[slot] = make_int2(sub[j],
                    (int)(((unsigned)rl[j] << 16) | f2h(alpha)));
            }
        }
    }
}

// ---------------------------------------------------------------------------
// Aggregation v4: persistent waves, 4 edges/iter, alpha precomputed -> no
// shuffle/sigmoid in loop. Per iter: prefetched 8B csr2 + 2 bf16 gathers + FMA.
// ---------------------------------------------------------------------------
__global__ __launch_bounds__(256) void agg_kernel(
    const int2*     __restrict__ csr2,   // [N_EDGE+4]
    const int*      __restrict__ offs,
    const ushort_t* __restrict__ hB,     // hidden bf16 [N_NODE][64]
    const ushort_t* __restrict__ relab,  // rela  bf16 [NVOCAB][64], L2-hot
    float* __restrict__ out)
{
    int lane = threadIdx.x & 63;
    int q    = lane >> 4;
    int l    = lane & 15;
    int f0   = l * 4;
    int wv = __builtin_amdgcn_readfirstlane((blockIdx.x * blockDim.x + threadIdx.x) >> 6);

    for (int n = wv; n < N_NODE; n += AGG_WAVES) {
        int i   = offs[n];
        int end = offs[n + 1];
        float4 acc = make_float4(0.f, 0.f, 0.f, 0.f);

        int2 e = csr2[min(i + q, N_EDGE + 3)];
        while (i < end) {
            int2 en = csr2[min(i + 4 + q, N_EDGE + 3)];
            float valid = (i + q < end) ? 1.0f : 0.0f;
            int sub = e.x;
            unsigned ey = (unsigned)e.y;
            float alpha = valid * h2f(ey & 0xFFFFu);
            int rl = (int)(ey >> 16);

            uint2 uh = *(const uint2*)(hB    + (size_t)sub * DIM + f0);
            uint2 ur = *(const uint2*)(relab + (size_t)rl  * DIM + f0);

            acc.x = fmaf(alpha, bflo(uh.x) + bflo(ur.x), acc.x);
            acc.y = fmaf(alpha, bfhi(uh.x) + bfhi(ur.x), acc.y);
            acc.z = fmaf(alpha, bflo(uh.y) + bflo(ur.y), acc.z);
            acc.w = fmaf(alpha, bfhi(uh.y) + bfhi(ur.y), acc.w);

            e = en;
            i += 4;
        }

        acc.x += __shfl_xor(acc.x, 16); acc.x += __shfl_xor(acc.x, 32);
        acc.y += __shfl_xor(acc.y, 16); acc.y += __shfl_xor(acc.y, 32);
        acc.z += __shfl_xor(acc.z, 16); acc.z += __shfl_xor(acc.z, 32);
        acc.w += __shfl_xor(acc.w, 16); acc.w += __shfl_xor(acc.w, 32);
        if (q == 0)
            *(float4*)(out + (size_t)n * DIM + f0) = acc;
    }
}

// ---------------------------------------------------------------------------
// Fallback (ws too small for CSR): wave-per-edge atomic kernel, bf16 tables.
// ---------------------------------------------------------------------------
__global__ __launch_bounds__(256) void edge_kernel(
    const int*      __restrict__ edges,
    const ushort_t* __restrict__ hB,
    const ushort_t* __restrict__ relab,
    const ushort_t* __restrict__ hsWs,
    const ushort_t* __restrict__ rel_preb,
    const ushort_t* __restrict__ qr_preb,
    const float*    __restrict__ wattn,
    float* __restrict__ out)
{
    int e = (blockIdx.x * blockDim.x + threadIdx.x) >> 6;
    if (e >= N_EDGE) return;
    int lane = threadIdx.x & 63;
    int r_i = edges[e * 6 + 0];
    int rl  = edges[e * 6 + 2];
    int sb  = edges[e * 6 + 4];
    int ob  = edges[e * 6 + 5];
    float hs = __uint_as_float(((unsigned)hB[(size_t)sb * DIM + lane]) << 16);
    float hr = __uint_as_float(((unsigned)relab[(size_t)rl * DIM + lane]) << 16);
    float p1 = __uint_as_float(((unsigned)hsWs[(size_t)sb * DIM + lane]) << 16);
    float p2 = __uint_as_float(((unsigned)rel_preb[(size_t)rl * DIM + lane]) << 16);
    float p3 = __uint_as_float(((unsigned)qr_preb[(size_t)r_i * DIM + lane]) << 16);
    float t = wattn[lane] * fmaxf(p1 + p2 + p3, 0.0f);
    #pragma unroll
    for (int off = 32; off; off >>= 1) t += __shfl_xor(t, off);
    float alpha = 1.0f / (1.0f + __expf(-t));
    atomicAdd(&out[(size_t)ob * DIM + lane], (hs + hr) * alpha);
}

extern "C" void kernel_launch(void* const* d_in, const int* in_sizes, int n_in,
                              void* d_out, int out_size, void* d_ws, size_t ws_size,
                              hipStream_t stream)
{
    const float* hidden = (const float*)d_in[0];
    const int*   q_rel  = (const int*)  d_in[1];
    const int*   edges  = (const int*)  d_in[2];
    const float* rela   = (const float*)d_in[3];
    const float* Ws     = (const float*)d_in[4];
    const float* Wr     = (const float*)d_in[5];
    const float* Wqr    = (const float*)d_in[6];
    const float* Wqr_b  = (const float*)d_in[7];
    const float* Wattn  = (const float*)d_in[8];
    const float* Wh     = (const float*)d_in[9];
    float* out = (float*)d_out;

    // ---- workspace layout ----
    ushort_t* qr_preb  = (ushort_t*)d_ws;                 // 256*64 bf16
    ushort_t* rel_preb = qr_preb + NB * DIM;              // 401*64 bf16
    ushort_t* relab    = rel_preb + NVOCAB * DIM;         // 401*64 bf16
    ushort_t* hsWs     = relab + NVOCAB * DIM;            // 100000*64 bf16
    ushort_t* hidb     = hsWs + (size_t)N_NODE * DIM;     // 100000*64 bf16
    int* rank    = (int*)(hidb + (size_t)N_NODE * DIM);   // N_EDGE
    int* deg     = rank + N_EDGE;                         // N_NODE
    int* offs    = deg + N_NODE;                          // N_NODE+1
    int* partial = offs + (N_NODE + 1);                   // 128 slots
    int* csr_raw = partial + 128;
    int2* csr2   = (int2*)(((uintptr_t)csr_raw + 7) & ~(uintptr_t)7);
    size_t csr_need = ((char*)csr2 - (char*)d_ws) + (size_t)(N_EDGE + 4) * sizeof(int2);
    bool use_csr = ws_size >= csr_need;

    // ---- precompute tables (out_mode 3 also emits bf16(X) for free) ----
    gemm64_kernel<<<(NVOCAB + 63) / 64, 256, 0, stream>>>(
        rela, nullptr, Wr, nullptr, rel_preb, relab, NVOCAB, 3);
    gemm64_kernel<<<(NB + 63) / 64, 256, 0, stream>>>(
        rela, q_rel, Wqr, Wqr_b, qr_preb, nullptr, NB, 2);
    gemm64_kernel<<<(N_NODE + 63) / 64, 256, 0, stream>>>(
        hidden, nullptr, Ws, nullptr, hsWs, hidb, N_NODE, 3);

    if (use_csr) {
        hipMemsetAsync(deg, 0, N_NODE * sizeof(int), stream);
        deg_rank_kernel<<<(N_EDGE + 255) / 256, 256, 0, stream>>>(edges, deg, rank);
        scan1_kernel<<<NCHUNK, SCAN_B, 0, stream>>>(deg, partial);
        scan2_kernel<<<1, 128, 0, stream>>>(partial, NCHUNK);
        scan3_kernel<<<NCHUNK, SCAN_B, 0, stream>>>(deg, partial, offs);
        // 32 edges per block (4 waves x 4 quarters x 2 edges)
        alpha_scatter_kernel<<<(N_EDGE + 31) / 32, 256, 0, stream>>>(
            edges, rank, offs, hsWs, rel_preb, qr_preb, Wattn, csr2);
        agg_kernel<<<AGG_WAVES / 4, 256, 0, stream>>>(csr2, offs, hidb, relab, out);
    } else {
        hipMemsetAsync(d_out, 0, (size_t)N_NODE * DIM * sizeof(float), stream);
        edge_kernel<<<(N_EDGE + 3) / 4, 256, 0, stream>>>(
            edges, hidb, relab, hsWs, rel_preb, qr_preb, Wattn, out);
    }

    // ---- out = relu(agg @ Wh^T), in-place ----
    gemm64_kernel<<<(N_NODE + 63) / 64, 256, 0, stream>>>(
        out, nullptr, Wh, nullptr, out, nullptr, N_NODE, 1);
}

// Round 9
// 276.258 us; speedup vs baseline: 2.4654x; 1.0865x over previous
//
#include <hip/hip_runtime.h>
#include <math.h>
#include <stdint.h>

#define N_NODE 100000
#define N_EDGE 1000000
#define DIM    64
#define NB     256
#define NVOCAB 401
#define SCAN_B 1024
#define NCHUNK ((N_NODE + SCAN_B - 1) / SCAN_B)
#define AGG_WAVES 8192

typedef short short8  __attribute__((ext_vector_type(8)));
typedef float floatx4 __attribute__((ext_vector_type(4)));
typedef unsigned short ushort_t;

__device__ inline unsigned short f2bf_rne(float f)
{
    unsigned u = __float_as_uint(f);
    unsigned r = u + 0x7FFF + ((u >> 16) & 1);
    return (unsigned short)(r >> 16);
}
__device__ inline float bflo(unsigned u) { return __uint_as_float(u << 16); }
__device__ inline float bfhi(unsigned u) { return __uint_as_float(u & 0xFFFF0000u); }
__device__ inline unsigned short f2h(float f)
{
    _Float16 h = (_Float16)f;
    unsigned short s; __builtin_memcpy(&s, &h, 2); return s;
}
__device__ inline float h2f(unsigned b)
{
    unsigned short s = (unsigned short)b;
    _Float16 h; __builtin_memcpy(&h, &s, 2); return (float)h;
}

// ---------------------------------------------------------------------------
// gemm64 body: Y[r][:] = act( X[idx?idx[r]:r] @ W^T + bias ), W 64x64 row-major.
// Split-bf16 (hi/lo) 3-MFMA => ~fp32 precision. 4 waves = 64 rows per call;
// wave w owns rows r0+16w..+15, computes all 64 cols (X read exactly once).
// In-place safe per-wave. out_mode: 0 fp32 | 1 fp32+relu | 2 bf16 |
// 3 bf16 + also store bf16(X rows) to Y2 (free from the loaded A frags).
// ---------------------------------------------------------------------------
__device__ inline void split8(float4 v0, float4 v1, short8& hi, short8& lo)
{
    float f[8] = {v0.x, v0.y, v0.z, v0.w, v1.x, v1.y, v1.z, v1.w};
    #pragma unroll
    for (int j = 0; j < 8; ++j) {
        unsigned u = __float_as_uint(f[j]);
        unsigned r = u + 0x7FFF + ((u >> 16) & 1);
        unsigned short h = (unsigned short)(r >> 16);
        float hf = __uint_as_float(((unsigned)h) << 16);
        float l  = f[j] - hf;
        unsigned u2 = __float_as_uint(l);
        unsigned r2 = u2 + 0x7FFF + ((u2 >> 16) & 1);
        hi[j] = (short)h;
        lo[j] = (short)(r2 >> 16);
    }
}

__device__ void gemm64_body(
    const float* __restrict__ X,
    const int*   __restrict__ idx,
    const float* __restrict__ W,
    const float* __restrict__ bias,
    void* __restrict__ Yv,
    ushort_t* __restrict__ Y2,
    int R, int out_mode, int blk)
{
    int wave = threadIdx.x >> 6;
    int lane = threadIdx.x & 63;
    int m    = lane & 15;
    int quad = lane >> 4;
    int r0   = blk * 64 + wave * 16;

    int r = r0 + m;
    int src = (r < R) ? (idx ? idx[r] : r) : 0;
    const float* xrow = X + (size_t)src * DIM + quad * 8;

    float4 a0[2], a1[2];
    #pragma unroll
    for (int c = 0; c < 2; ++c) {
        a0[c] = *(const float4*)(xrow + 32 * c);
        a1[c] = *(const float4*)(xrow + 32 * c + 4);
    }
    short8 ah[2], al[2];
    #pragma unroll
    for (int c = 0; c < 2; ++c) split8(a0[c], a1[c], ah[c], al[c]);

    if (out_mode == 3 && r < R) {   // bf16 copy of X rows, free from A frags
        #pragma unroll
        for (int c = 0; c < 2; ++c)
            *(short8*)(Y2 + (size_t)r * DIM + 32 * c + quad * 8) = ah[c];
    }

    floatx4 acc[4] = {{0,0,0,0},{0,0,0,0},{0,0,0,0},{0,0,0,0}};
    #pragma unroll
    for (int g = 0; g < 4; ++g) {
        const float* wrow = W + (size_t)(g * 16 + m) * DIM + quad * 8;
        #pragma unroll
        for (int c = 0; c < 2; ++c) {
            float4 b0 = *(const float4*)(wrow + 32 * c);
            float4 b1 = *(const float4*)(wrow + 32 * c + 4);
            short8 bh, bl;
            split8(b0, b1, bh, bl);
            acc[g] = __builtin_amdgcn_mfma_f32_16x16x32_bf16(ah[c], bh, acc[g], 0, 0, 0);
            acc[g] = __builtin_amdgcn_mfma_f32_16x16x32_bf16(ah[c], bl, acc[g], 0, 0, 0);
            acc[g] = __builtin_amdgcn_mfma_f32_16x16x32_bf16(al[c], bh, acc[g], 0, 0, 0);
        }
    }

    #pragma unroll
    for (int g = 0; g < 4; ++g) {
        float bv = bias ? bias[g * 16 + m] : 0.0f;
        #pragma unroll
        for (int reg = 0; reg < 4; ++reg) {
            int rr = r0 + quad * 4 + reg;        // D row = quad*4+reg (own rows)
            if (rr < R) {
                float v = acc[g][reg] + bv;      // D col = g*16 + (lane&15)
                if (out_mode == 1) v = fmaxf(v, 0.0f);
                if (out_mode >= 2)
                    ((ushort_t*)Yv)[(size_t)rr * DIM + g * 16 + m] = f2bf_rne(v);
                else
                    ((float*)Yv)[(size_t)rr * DIM + g * 16 + m] = v;
            }
        }
    }
}

__global__ __launch_bounds__(256) void gemm64_kernel(
    const float* __restrict__ X,
    const int*   __restrict__ idx,
    const float* __restrict__ W,
    const float* __restrict__ bias,
    void* __restrict__ Yv,
    ushort_t* __restrict__ Y2,
    int R, int out_mode)
{
    gemm64_body(X, idx, W, bias, Yv, Y2, R, out_mode, blockIdx.x);
}

// ---------------------------------------------------------------------------
// prep: ONE heterogeneous launch for the 4 independent preprocessing jobs.
// Blocks [0,G1): hsWs/hidb gemm; [G1,G1+7): rel tables gemm; next 4: qr gemm;
// rest: deg+rank pass (atomic-latency-bound, hides under the MFMA gemms --
// MFMA/VALU/VMEM pipes co-schedule across waves on a CU).
// ---------------------------------------------------------------------------
#define G1 ((N_NODE + 63) / 64)            // 1563
#define G2 ((NVOCAB + 63) / 64)            // 7
#define G3 (NB / 64)                       // 4
#define GD ((N_EDGE + 255) / 256)          // 3907
#define PREP_GRID (G1 + G2 + G3 + GD)

__global__ __launch_bounds__(256) void prep_kernel(
    const float* __restrict__ hidden,
    const float* __restrict__ rela,
    const int*   __restrict__ q_rel,
    const float* __restrict__ Ws,
    const float* __restrict__ Wr,
    const float* __restrict__ Wqr,
    const float* __restrict__ Wqr_b,
    ushort_t* __restrict__ hsWs,
    ushort_t* __restrict__ hidb,
    ushort_t* __restrict__ rel_preb,
    ushort_t* __restrict__ relab,
    ushort_t* __restrict__ qr_preb,
    const int* __restrict__ edges,
    int* __restrict__ deg,
    int* __restrict__ rank)
{
    int b = blockIdx.x;
    if (b < G1) {
        gemm64_body(hidden, nullptr, Ws, nullptr, hsWs, hidb, N_NODE, 3, b);
    } else if (b < G1 + G2) {
        gemm64_body(rela, nullptr, Wr, nullptr, rel_preb, relab, NVOCAB, 3, b - G1);
    } else if (b < G1 + G2 + G3) {
        gemm64_body(rela, q_rel, Wqr, Wqr_b, qr_preb, nullptr, NB, 2, b - G1 - G2);
    } else {
        int e = (b - G1 - G2 - G3) * 256 + threadIdx.x;
        if (e < N_EDGE) {
            int2 so = *(const int2*)(edges + (size_t)e * 6 + 4);  // (sub, obj)
            rank[e] = atomicAdd(&deg[so.y], 1);
        }
    }
}

// ---------------------------------------------------------------------------
// CSR scan pipeline
// ---------------------------------------------------------------------------
__global__ __launch_bounds__(SCAN_B) void scan1_kernel(const int* __restrict__ deg,
                                                       int* __restrict__ partial)
{
    __shared__ int s[SCAN_B];
    int g = blockIdx.x * SCAN_B + threadIdx.x;
    s[threadIdx.x] = (g < N_NODE) ? deg[g] : 0;
    __syncthreads();
    for (int off = SCAN_B / 2; off; off >>= 1) {
        if (threadIdx.x < off) s[threadIdx.x] += s[threadIdx.x + off];
        __syncthreads();
    }
    if (threadIdx.x == 0) partial[blockIdx.x] = s[0];
}

__global__ __launch_bounds__(128) void scan2_kernel(int* __restrict__ partial, int n)
{
    __shared__ int s[128];
    int t = threadIdx.x;
    int v = (t < n) ? partial[t] : 0;
    s[t] = v;
    __syncthreads();
    for (int off = 1; off < 128; off <<= 1) {
        int add = (t >= off) ? s[t - off] : 0;
        __syncthreads();
        s[t] += add;
        __syncthreads();
    }
    if (t < n) partial[t] = s[t] - v;   // exclusive
}

__global__ __launch_bounds__(SCAN_B) void scan3_kernel(const int* __restrict__ deg,
                                                       const int* __restrict__ partial,
                                                       int* __restrict__ offs)
{
    __shared__ int s[SCAN_B];
    int g = blockIdx.x * SCAN_B + threadIdx.x;
    s[threadIdx.x] = (g < N_NODE) ? deg[g] : 0;
    __syncthreads();
    for (int off = 1; off < SCAN_B; off <<= 1) {
        int add = ((int)threadIdx.x >= off) ? s[threadIdx.x - off] : 0;
        __syncthreads();
        s[threadIdx.x] += add;
        __syncthreads();
    }
    if (g < N_NODE) {
        offs[g + 1] = partial[blockIdx.x] + s[threadIdx.x];
        if (g == 0) offs[0] = 0;
    }
}

// ---------------------------------------------------------------------------
// alpha + scatter v2: quarter-wave (16 lanes/edge), 4 edges per quarter
// (independent chains -> 4x MLP), 16 edges/wave, 64 edges/block.
// N_EDGE = 64*15625 exactly -> no tail. Atomic-free: slot = offs[obj]+rank[e].
// ---------------------------------------------------------------------------
__global__ __launch_bounds__(256) void alpha_scatter_kernel(
    const int*      __restrict__ edges,
    const int*      __restrict__ rank,
    const int*      __restrict__ offs,
    const ushort_t* __restrict__ hsWs,      // bf16 [N_NODE][64]
    const ushort_t* __restrict__ rel_preb,  // bf16 [NVOCAB][64]
    const ushort_t* __restrict__ qr_preb,   // bf16 [NB][64]
    const float*    __restrict__ wattn,
    int2*           __restrict__ csr2)
{
    int tid = blockIdx.x * 256 + threadIdx.x;
    if (tid < 4) csr2[N_EDGE + tid] = make_int2(0, 0);

    int wave = threadIdx.x >> 6;
    int lane = threadIdx.x & 63;
    int q    = lane >> 4;
    int l    = lane & 15;
    int f0   = l * 4;
    int e0   = (blockIdx.x * 4 + wave) * 16 + q * 4;   // this quarter: e0..e0+3

    float4 wa = *(const float4*)(wattn + f0);

    int   sub[4], rl[4], ob[4];
    float t[4];
    #pragma unroll
    for (int j = 0; j < 4; ++j) {
        int e = e0 + j;                                // always < N_EDGE (exact grid)
        int2 ab = *(const int2*)(edges + (size_t)e * 6);      // r_idx
        int2 cd = *(const int2*)(edges + (size_t)e * 6 + 2);  // rel
        int2 ef = *(const int2*)(edges + (size_t)e * 6 + 4);  // sub, obj
        rl[j] = cd.x; sub[j] = ef.x; ob[j] = ef.y;

        uint2 uh = *(const uint2*)(hsWs     + (size_t)ef.x * DIM + f0);
        uint2 ur = *(const uint2*)(rel_preb + (size_t)cd.x * DIM + f0);
        uint2 uq = *(const uint2*)(qr_preb  + (size_t)ab.x * DIM + f0);

        float tt =  fmaxf(bflo(uh.x) + bflo(ur.x) + bflo(uq.x), 0.f) * wa.x;
        tt = fmaf(fmaxf(bfhi(uh.x) + bfhi(ur.x) + bfhi(uq.x), 0.f), wa.y, tt);
        tt = fmaf(fmaxf(bflo(uh.y) + bflo(ur.y) + bflo(uq.y), 0.f), wa.z, tt);
        tt = fmaf(fmaxf(bfhi(uh.y) + bfhi(ur.y) + bfhi(uq.y), 0.f), wa.w, tt);
        t[j] = tt;
    }
    #pragma unroll
    for (int j = 0; j < 4; ++j) {
        t[j] += __shfl_xor(t[j], 1);
        t[j] += __shfl_xor(t[j], 2);
        t[j] += __shfl_xor(t[j], 4);
        t[j] += __shfl_xor(t[j], 8);              // reduced within quarter
    }

    if (l == 0) {
        int4 rk = *(const int4*)(rank + e0);      // e0 % 4 == 0 -> aligned
        int rka[4] = {rk.x, rk.y, rk.z, rk.w};
        #pragma unroll
        for (int j = 0; j < 4; ++j) {
            float alpha = 1.0f / (1.0f + __expf(-t[j]));
            int slot = offs[ob[j]] + rka[j];
            csr2[slot] = make_int2(sub[j],
                (int)(((unsigned)rl[j] << 16) | f2h(alpha)));
        }
    }
}

// ---------------------------------------------------------------------------
// Aggregation v5: persistent waves, 8 edges/iter (2 per quarter, independent
// chains), csr2 prefetch, next-node offs prefetch (kills the per-node serial
// ~200cyc s_load round-trip; ~12 nodes/wave).
// ---------------------------------------------------------------------------
__global__ __launch_bounds__(256) void agg_kernel(
    const int2*     __restrict__ csr2,   // [N_EDGE+4]
    const int*      __restrict__ offs,
    const ushort_t* __restrict__ hB,     // hidden bf16 [N_NODE][64]
    const ushort_t* __restrict__ relab,  // rela  bf16 [NVOCAB][64], L2-hot
    float* __restrict__ out)
{
    int lane = threadIdx.x & 63;
    int q    = lane >> 4;
    int l    = lane & 15;
    int f0   = l * 4;
    int wv = __builtin_amdgcn_readfirstlane((blockIdx.x * blockDim.x + threadIdx.x) >> 6);

    int i   = offs[wv];
    int end = offs[wv + 1];
    for (int n = wv; n < N_NODE; n += AGG_WAVES) {
        // prefetch next node's range while this node streams
        int nn = n + AGG_WAVES;
        int ni = 0, ne = 0;
        if (nn < N_NODE) { ni = offs[nn]; ne = offs[nn + 1]; }

        float4 acc = make_float4(0.f, 0.f, 0.f, 0.f);
        int2 e0 = csr2[min(i + q,     N_EDGE + 3)];
        int2 e1 = csr2[min(i + 4 + q, N_EDGE + 3)];
        while (i < end) {
            int2 f0e = csr2[min(i + 8 + q,  N_EDGE + 3)];
            int2 f1e = csr2[min(i + 12 + q, N_EDGE + 3)];
            float v0 = (i + q < end)     ? 1.0f : 0.0f;
            float v1 = (i + 4 + q < end) ? 1.0f : 0.0f;

            unsigned ey0 = (unsigned)e0.y, ey1 = (unsigned)e1.y;
            float al0 = v0 * h2f(ey0 & 0xFFFFu);
            float al1 = v1 * h2f(ey1 & 0xFFFFu);

            uint2 uh0 = *(const uint2*)(hB    + (size_t)e0.x        * DIM + f0);
            uint2 ur0 = *(const uint2*)(relab + (size_t)(ey0 >> 16) * DIM + f0);
            uint2 uh1 = *(const uint2*)(hB    + (size_t)e1.x        * DIM + f0);
            uint2 ur1 = *(const uint2*)(relab + (size_t)(ey1 >> 16) * DIM + f0);

            acc.x = fmaf(al0, bflo(uh0.x) + bflo(ur0.x), acc.x);
            acc.y = fmaf(al0, bfhi(uh0.x) + bfhi(ur0.x), acc.y);
            acc.z = fmaf(al0, bflo(uh0.y) + bflo(ur0.y), acc.z);
            acc.w = fmaf(al0, bfhi(uh0.y) + bfhi(ur0.y), acc.w);
            acc.x = fmaf(al1, bflo(uh1.x) + bflo(ur1.x), acc.x);
            acc.y = fmaf(al1, bfhi(uh1.x) + bfhi(ur1.x), acc.y);
            acc.z = fmaf(al1, bflo(uh1.y) + bflo(ur1.y), acc.z);
            acc.w = fmaf(al1, bfhi(uh1.y) + bfhi(ur1.y), acc.w);

            e0 = f0e; e1 = f1e;
            i += 8;
        }

        acc.x += __shfl_xor(acc.x, 16); acc.x += __shfl_xor(acc.x, 32);
        acc.y += __shfl_xor(acc.y, 16); acc.y += __shfl_xor(acc.y, 32);
        acc.z += __shfl_xor(acc.z, 16); acc.z += __shfl_xor(acc.z, 32);
        acc.w += __shfl_xor(acc.w, 16); acc.w += __shfl_xor(acc.w, 32);
        if (q == 0)
            *(float4*)(out + (size_t)n * DIM + f0) = acc;

        i = ni; end = ne;
    }
}

// ---------------------------------------------------------------------------
// Fallback (ws too small for CSR): wave-per-edge atomic kernel, bf16 tables.
// ---------------------------------------------------------------------------
__global__ __launch_bounds__(256) void edge_kernel(
    const int*      __restrict__ edges,
    const ushort_t* __restrict__ hB,
    const ushort_t* __restrict__ relab,
    const ushort_t* __restrict__ hsWs,
    const ushort_t* __restrict__ rel_preb,
    const ushort_t* __restrict__ qr_preb,
    const float*    __restrict__ wattn,
    float* __restrict__ out)
{
    int e = (blockIdx.x * blockDim.x + threadIdx.x) >> 6;
    if (e >= N_EDGE) return;
    int lane = threadIdx.x & 63;
    int r_i = edges[e * 6 + 0];
    int rl  = edges[e * 6 + 2];
    int sb  = edges[e * 6 + 4];
    int ob  = edges[e * 6 + 5];
    float hs = __uint_as_float(((unsigned)hB[(size_t)sb * DIM + lane]) << 16);
    float hr = __uint_as_float(((unsigned)relab[(size_t)rl * DIM + lane]) << 16);
    float p1 = __uint_as_float(((unsigned)hsWs[(size_t)sb * DIM + lane]) << 16);
    float p2 = __uint_as_float(((unsigned)rel_preb[(size_t)rl * DIM + lane]) << 16);
    float p3 = __uint_as_float(((unsigned)qr_preb[(size_t)r_i * DIM + lane]) << 16);
    float t = wattn[lane] * fmaxf(p1 + p2 + p3, 0.0f);
    #pragma unroll
    for (int off = 32; off; off >>= 1) t += __shfl_xor(t, off);
    float alpha = 1.0f / (1.0f + __expf(-t));
    atomicAdd(&out[(size_t)ob * DIM + lane], (hs + hr) * alpha);
}

extern "C" void kernel_launch(void* const* d_in, const int* in_sizes, int n_in,
                              void* d_out, int out_size, void* d_ws, size_t ws_size,
                              hipStream_t stream)
{
    const float* hidden = (const float*)d_in[0];
    const int*   q_rel  = (const int*)  d_in[1];
    const int*   edges  = (const int*)  d_in[2];
    const float* rela   = (const float*)d_in[3];
    const float* Ws     = (const float*)d_in[4];
    const float* Wr     = (const float*)d_in[5];
    const float* Wqr    = (const float*)d_in[6];
    const float* Wqr_b  = (const float*)d_in[7];
    const float* Wattn  = (const float*)d_in[8];
    const float* Wh     = (const float*)d_in[9];
    float* out = (float*)d_out;

    // ---- workspace layout ----
    ushort_t* qr_preb  = (ushort_t*)d_ws;                 // 256*64 bf16
    ushort_t* rel_preb = qr_preb + NB * DIM;              // 401*64 bf16
    ushort_t* relab    = rel_preb + NVOCAB * DIM;         // 401*64 bf16
    ushort_t* hsWs     = relab + NVOCAB * DIM;            // 100000*64 bf16
    ushort_t* hidb     = hsWs + (size_t)N_NODE * DIM;     // 100000*64 bf16
    int* rank    = (int*)(hidb + (size_t)N_NODE * DIM);   // N_EDGE
    int* deg     = rank + N_EDGE;                         // N_NODE
    int* offs    = deg + N_NODE;                          // N_NODE+1
    int* partial = offs + (N_NODE + 1);                   // 128 slots
    int* csr_raw = partial + 128;
    int2* csr2   = (int2*)(((uintptr_t)csr_raw + 7) & ~(uintptr_t)7);
    size_t csr_need = ((char*)csr2 - (char*)d_ws) + (size_t)(N_EDGE + 4) * sizeof(int2);
    bool use_csr = ws_size >= csr_need;

    if (use_csr) {
        hipMemsetAsync(deg, 0, N_NODE * sizeof(int), stream);
        // one launch: 3 gemms + deg/rank, all independent, co-scheduled
        prep_kernel<<<PREP_GRID, 256, 0, stream>>>(
            hidden, rela, q_rel, Ws, Wr, Wqr, Wqr_b,
            hsWs, hidb, rel_preb, relab, qr_preb, edges, deg, rank);
        scan1_kernel<<<NCHUNK, SCAN_B, 0, stream>>>(deg, partial);
        scan2_kernel<<<1, 128, 0, stream>>>(partial, NCHUNK);
        scan3_kernel<<<NCHUNK, SCAN_B, 0, stream>>>(deg, partial, offs);
        // 64 edges per block (4 waves x 4 quarters x 4 edges); exact division
        alpha_scatter_kernel<<<N_EDGE / 64, 256, 0, stream>>>(
            edges, rank, offs, hsWs, rel_preb, qr_preb, Wattn, csr2);
        agg_kernel<<<AGG_WAVES / 4, 256, 0, stream>>>(csr2, offs, hidb, relab, out);
    } else {
        gemm64_kernel<<<(NVOCAB + 63) / 64, 256, 0, stream>>>(
            rela, nullptr, Wr, nullptr, rel_preb, relab, NVOCAB, 3);
        gemm64_kernel<<<(NB + 63) / 64, 256, 0, stream>>>(
            rela, q_rel, Wqr, Wqr_b, qr_preb, nullptr, NB, 2);
        gemm64_kernel<<<(N_NODE + 63) / 64, 256, 0, stream>>>(
            hidden, nullptr, Ws, nullptr, hsWs, hidb, N_NODE, 3);
        hipMemsetAsync(d_out, 0, (size_t)N_NODE * DIM * sizeof(float), stream);
        edge_kernel<<<(N_EDGE + 3) / 4, 256, 0, stream>>>(
            edges, hidb, relab, hsWs, rel_preb, qr_preb, Wattn, out);
    }

    // ---- out = relu(agg @ Wh^T), in-place ----
    gemm64_kernel<<<(N_NODE + 63) / 64, 256, 0, stream>>>(
        out, nullptr, Wh, nullptr, out, nullptr, N_NODE, 1);
}

// Round 10
// 265.914 us; speedup vs baseline: 2.5613x; 1.0389x over previous
//
#include <hip/hip_runtime.h>
#include <math.h>
#include <stdint.h>

#define N_NODE 100000
#define N_EDGE 1000000
#define DIM    64
#define NB     256
#define NVOCAB 401
#define SCAN_B 1024
#define NCHUNK ((N_NODE + SCAN_B - 1) / SCAN_B)
#define AGG_WAVES 8192

typedef short short8  __attribute__((ext_vector_type(8)));
typedef float floatx4 __attribute__((ext_vector_type(4)));
typedef unsigned short ushort_t;

__device__ inline unsigned short f2bf_rne(float f)
{
    unsigned u = __float_as_uint(f);
    unsigned r = u + 0x7FFF + ((u >> 16) & 1);
    return (unsigned short)(r >> 16);
}
__device__ inline float bflo(unsigned u) { return __uint_as_float(u << 16); }
__device__ inline float bfhi(unsigned u) { return __uint_as_float(u & 0xFFFF0000u); }
__device__ inline unsigned short f2h(float f)
{
    _Float16 h = (_Float16)f;
    unsigned short s; __builtin_memcpy(&s, &h, 2); return s;
}
__device__ inline float h2f(unsigned b)
{
    unsigned short s = (unsigned short)b;
    _Float16 h; __builtin_memcpy(&h, &s, 2); return (float)h;
}

// ---------------------------------------------------------------------------
// gemm64 body: Y[r][:] = act( X[idx?idx[r]:r] @ W^T + bias ), W 64x64 row-major.
// Split-bf16 (hi/lo) 3-MFMA => ~fp32 precision. 4 waves = 64 rows per call;
// wave w owns rows r0+16w..+15, computes all 64 cols (X read exactly once).
// In-place safe per-wave. out_mode: 0 fp32 | 1 fp32+relu | 2 bf16 |
// 3 bf16 + also store bf16(X rows) to Y2 (free from the loaded A frags).
// ---------------------------------------------------------------------------
__device__ inline void split8(float4 v0, float4 v1, short8& hi, short8& lo)
{
    float f[8] = {v0.x, v0.y, v0.z, v0.w, v1.x, v1.y, v1.z, v1.w};
    #pragma unroll
    for (int j = 0; j < 8; ++j) {
        unsigned u = __float_as_uint(f[j]);
        unsigned r = u + 0x7FFF + ((u >> 16) & 1);
        unsigned short h = (unsigned short)(r >> 16);
        float hf = __uint_as_float(((unsigned)h) << 16);
        float l  = f[j] - hf;
        unsigned u2 = __float_as_uint(l);
        unsigned r2 = u2 + 0x7FFF + ((u2 >> 16) & 1);
        hi[j] = (short)h;
        lo[j] = (short)(r2 >> 16);
    }
}

__device__ void gemm64_body(
    const float* __restrict__ X,
    const int*   __restrict__ idx,
    const float* __restrict__ W,
    const float* __restrict__ bias,
    void* __restrict__ Yv,
    ushort_t* __restrict__ Y2,
    int R, int out_mode, int blk)
{
    int wave = threadIdx.x >> 6;
    int lane = threadIdx.x & 63;
    int m    = lane & 15;
    int quad = lane >> 4;
    int r0   = blk * 64 + wave * 16;

    int r = r0 + m;
    int src = (r < R) ? (idx ? idx[r] : r) : 0;
    const float* xrow = X + (size_t)src * DIM + quad * 8;

    float4 a0[2], a1[2];
    #pragma unroll
    for (int c = 0; c < 2; ++c) {
        a0[c] = *(const float4*)(xrow + 32 * c);
        a1[c] = *(const float4*)(xrow + 32 * c + 4);
    }
    short8 ah[2], al[2];
    #pragma unroll
    for (int c = 0; c < 2; ++c) split8(a0[c], a1[c], ah[c], al[c]);

    if (out_mode == 3 && r < R) {   // bf16 copy of X rows, free from A frags
        #pragma unroll
        for (int c = 0; c < 2; ++c)
            *(short8*)(Y2 + (size_t)r * DIM + 32 * c + quad * 8) = ah[c];
    }

    floatx4 acc[4] = {{0,0,0,0},{0,0,0,0},{0,0,0,0},{0,0,0,0}};
    #pragma unroll
    for (int g = 0; g < 4; ++g) {
        const float* wrow = W + (size_t)(g * 16 + m) * DIM + quad * 8;
        #pragma unroll
        for (int c = 0; c < 2; ++c) {
            float4 b0 = *(const float4*)(wrow + 32 * c);
            float4 b1 = *(const float4*)(wrow + 32 * c + 4);
            short8 bh, bl;
            split8(b0, b1, bh, bl);
            acc[g] = __builtin_amdgcn_mfma_f32_16x16x32_bf16(ah[c], bh, acc[g], 0, 0, 0);
            acc[g] = __builtin_amdgcn_mfma_f32_16x16x32_bf16(ah[c], bl, acc[g], 0, 0, 0);
            acc[g] = __builtin_amdgcn_mfma_f32_16x16x32_bf16(al[c], bh, acc[g], 0, 0, 0);
        }
    }

    #pragma unroll
    for (int g = 0; g < 4; ++g) {
        float bv = bias ? bias[g * 16 + m] : 0.0f;
        #pragma unroll
        for (int reg = 0; reg < 4; ++reg) {
            int rr = r0 + quad * 4 + reg;        // D row = quad*4+reg (own rows)
            if (rr < R) {
                float v = acc[g][reg] + bv;      // D col = g*16 + (lane&15)
                if (out_mode == 1) v = fmaxf(v, 0.0f);
                if (out_mode >= 2)
                    ((ushort_t*)Yv)[(size_t)rr * DIM + g * 16 + m] = f2bf_rne(v);
                else
                    ((float*)Yv)[(size_t)rr * DIM + g * 16 + m] = v;
            }
        }
    }
}

__global__ __launch_bounds__(256) void gemm64_kernel(
    const float* __restrict__ X,
    const int*   __restrict__ idx,
    const float* __restrict__ W,
    const float* __restrict__ bias,
    void* __restrict__ Yv,
    ushort_t* __restrict__ Y2,
    int R, int out_mode)
{
    gemm64_body(X, idx, W, bias, Yv, Y2, R, out_mode, blockIdx.x);
}

// ---------------------------------------------------------------------------
// prep: ONE heterogeneous launch. Blocks 0..10: small rel/qr gemms. The rest
// BRESENHAM-INTERLEAVES hsWs-gemm blocks (G1) with deg/rank blocks (GD4) so
// atomic-latency waves co-reside with MFMA/memory waves on every CU (R9 had
// them phase-separated by dispatch order -> no overlap, 61us all-pipes-idle).
// Deg blocks process 4 edges/thread = 4 independent atomic RTs in flight.
// ---------------------------------------------------------------------------
#define G1 ((N_NODE + 63) / 64)            // 1563
#define G2 ((NVOCAB + 63) / 64)            // 7
#define G3 (NB / 64)                       // 4
#define GSMALL (G2 + G3)                   // 11
#define GD4 ((N_EDGE + 1023) / 1024)       // 977 (4 edges/thread)
#define PREP_T (G1 + GD4)                  // 2540
#define PREP_GRID (GSMALL + PREP_T)

__global__ __launch_bounds__(256) void prep_kernel(
    const float* __restrict__ hidden,
    const float* __restrict__ rela,
    const int*   __restrict__ q_rel,
    const float* __restrict__ Ws,
    const float* __restrict__ Wr,
    const float* __restrict__ Wqr,
    const float* __restrict__ Wqr_b,
    ushort_t* __restrict__ hsWs,
    ushort_t* __restrict__ hidb,
    ushort_t* __restrict__ rel_preb,
    ushort_t* __restrict__ relab,
    ushort_t* __restrict__ qr_preb,
    const int* __restrict__ edges,
    int* __restrict__ deg,
    int* __restrict__ rank)
{
    int b = blockIdx.x;
    if (b < G2) {
        gemm64_body(rela, nullptr, Wr, nullptr, rel_preb, relab, NVOCAB, 3, b);
    } else if (b < GSMALL) {
        gemm64_body(rela, q_rel, Wqr, Wqr_b, qr_preb, nullptr, NB, 2, b - G2);
    } else {
        int bp = b - GSMALL;
        int prior = (int)(((long)bp * GD4) / PREP_T);        // deg blocks before bp
        int nxt   = (int)(((long)(bp + 1) * GD4) / PREP_T);
        if (nxt > prior) {
            // deg/rank block #prior: 4 edges per thread, coalesced rank writes
            int base = prior * 1024 + threadIdx.x;
            #pragma unroll
            for (int k = 0; k < 4; ++k) {
                int e = base + k * 256;
                if (e < N_EDGE) {
                    int2 so = *(const int2*)(edges + (size_t)e * 6 + 4);  // (sub, obj)
                    rank[e] = atomicAdd(&deg[so.y], 1);
                }
            }
        } else {
            gemm64_body(hidden, nullptr, Ws, nullptr, hsWs, hidb, N_NODE, 3, bp - prior);
        }
    }
}

// ---------------------------------------------------------------------------
// CSR scan pipeline
// ---------------------------------------------------------------------------
__global__ __launch_bounds__(SCAN_B) void scan1_kernel(const int* __restrict__ deg,
                                                       int* __restrict__ partial)
{
    __shared__ int s[SCAN_B];
    int g = blockIdx.x * SCAN_B + threadIdx.x;
    s[threadIdx.x] = (g < N_NODE) ? deg[g] : 0;
    __syncthreads();
    for (int off = SCAN_B / 2; off; off >>= 1) {
        if (threadIdx.x < off) s[threadIdx.x] += s[threadIdx.x + off];
        __syncthreads();
    }
    if (threadIdx.x == 0) partial[blockIdx.x] = s[0];
}

__global__ __launch_bounds__(128) void scan2_kernel(int* __restrict__ partial, int n)
{
    __shared__ int s[128];
    int t = threadIdx.x;
    int v = (t < n) ? partial[t] : 0;
    s[t] = v;
    __syncthreads();
    for (int off = 1; off < 128; off <<= 1) {
        int add = (t >= off) ? s[t - off] : 0;
        __syncthreads();
        s[t] += add;
        __syncthreads();
    }
    if (t < n) partial[t] = s[t] - v;   // exclusive
}

__global__ __launch_bounds__(SCAN_B) void scan3_kernel(const int* __restrict__ deg,
                                                       const int* __restrict__ partial,
                                                       int* __restrict__ offs)
{
    __shared__ int s[SCAN_B];
    int g = blockIdx.x * SCAN_B + threadIdx.x;
    s[threadIdx.x] = (g < N_NODE) ? deg[g] : 0;
    __syncthreads();
    for (int off = 1; off < SCAN_B; off <<= 1) {
        int add = ((int)threadIdx.x >= off) ? s[threadIdx.x - off] : 0;
        __syncthreads();
        s[threadIdx.x] += add;
        __syncthreads();
    }
    if (g < N_NODE) {
        offs[g + 1] = partial[blockIdx.x] + s[threadIdx.x];
        if (g == 0) offs[0] = 0;
    }
}

// ---------------------------------------------------------------------------
// alpha + scatter v2: quarter-wave (16 lanes/edge), 4 edges per quarter
// (independent chains -> 4x MLP), 16 edges/wave, 64 edges/block.
// N_EDGE = 64*15625 exactly -> no tail. Atomic-free: slot = offs[obj]+rank[e].
// ---------------------------------------------------------------------------
__global__ __launch_bounds__(256) void alpha_scatter_kernel(
    const int*      __restrict__ edges,
    const int*      __restrict__ rank,
    const int*      __restrict__ offs,
    const ushort_t* __restrict__ hsWs,      // bf16 [N_NODE][64]
    const ushort_t* __restrict__ rel_preb,  // bf16 [NVOCAB][64]
    const ushort_t* __restrict__ qr_preb,   // bf16 [NB][64]
    const float*    __restrict__ wattn,
    int2*           __restrict__ csr2)
{
    int tid = blockIdx.x * 256 + threadIdx.x;
    if (tid < 4) csr2[N_EDGE + tid] = make_int2(0, 0);

    int wave = threadIdx.x >> 6;
    int lane = threadIdx.x & 63;
    int q    = lane >> 4;
    int l    = lane & 15;
    int f0   = l * 4;
    int e0   = (blockIdx.x * 4 + wave) * 16 + q * 4;   // this quarter: e0..e0+3

    float4 wa = *(const float4*)(wattn + f0);

    int   sub[4], rl[4], ob[4];
    float t[4];
    #pragma unroll
    for (int j = 0; j < 4; ++j) {
        int e = e0 + j;                                // always < N_EDGE (exact grid)
        int2 ab = *(const int2*)(edges + (size_t)e * 6);      // r_idx
        int2 cd = *(const int2*)(edges + (size_t)e * 6 + 2);  // rel
        int2 ef = *(const int2*)(edges + (size_t)e * 6 + 4);  // sub, obj
        rl[j] = cd.x; sub[j] = ef.x; ob[j] = ef.y;

        uint2 uh = *(const uint2*)(hsWs     + (size_t)ef.x * DIM + f0);
        uint2 ur = *(const uint2*)(rel_preb + (size_t)cd.x * DIM + f0);
        uint2 uq = *(const uint2*)(qr_preb  + (size_t)ab.x * DIM + f0);

        float tt =  fmaxf(bflo(uh.x) + bflo(ur.x) + bflo(uq.x), 0.f) * wa.x;
        tt = fmaf(fmaxf(bfhi(uh.x) + bfhi(ur.x) + bfhi(uq.x), 0.f), wa.y, tt);
        tt = fmaf(fmaxf(bflo(uh.y) + bflo(ur.y) + bflo(uq.y), 0.f), wa.z, tt);
        tt = fmaf(fmaxf(bfhi(uh.y) + bfhi(ur.y) + bfhi(uq.y), 0.f), wa.w, tt);
        t[j] = tt;
    }
    #pragma unroll
    for (int j = 0; j < 4; ++j) {
        t[j] += __shfl_xor(t[j], 1);
        t[j] += __shfl_xor(t[j], 2);
        t[j] += __shfl_xor(t[j], 4);
        t[j] += __shfl_xor(t[j], 8);              // reduced within quarter
    }

    if (l == 0) {
        int4 rk = *(const int4*)(rank + e0);      // e0 % 4 == 0 -> aligned
        int rka[4] = {rk.x, rk.y, rk.z, rk.w};
        #pragma unroll
        for (int j = 0; j < 4; ++j) {
            float alpha = 1.0f / (1.0f + __expf(-t[j]));
            int slot = offs[ob[j]] + rka[j];
            csr2[slot] = make_int2(sub[j],
                (int)(((unsigned)rl[j] << 16) | f2h(alpha)));
        }
    }
}

// ---------------------------------------------------------------------------
// Aggregation v5: persistent waves, 8 edges/iter (2 per quarter, independent
// chains), csr2 prefetch, next-node offs prefetch.
// ---------------------------------------------------------------------------
__global__ __launch_bounds__(256) void agg_kernel(
    const int2*     __restrict__ csr2,   // [N_EDGE+4]
    const int*      __restrict__ offs,
    const ushort_t* __restrict__ hB,     // hidden bf16 [N_NODE][64]
    const ushort_t* __restrict__ relab,  // rela  bf16 [NVOCAB][64], L2-hot
    float* __restrict__ out)
{
    int lane = threadIdx.x & 63;
    int q    = lane >> 4;
    int l    = lane & 15;
    int f0   = l * 4;
    int wv = __builtin_amdgcn_readfirstlane((blockIdx.x * blockDim.x + threadIdx.x) >> 6);

    int i   = offs[wv];
    int end = offs[wv + 1];
    for (int n = wv; n < N_NODE; n += AGG_WAVES) {
        int nn = n + AGG_WAVES;
        int ni = 0, ne = 0;
        if (nn < N_NODE) { ni = offs[nn]; ne = offs[nn + 1]; }

        float4 acc = make_float4(0.f, 0.f, 0.f, 0.f);
        int2 e0 = csr2[min(i + q,     N_EDGE + 3)];
        int2 e1 = csr2[min(i + 4 + q, N_EDGE + 3)];
        while (i < end) {
            int2 f0e = csr2[min(i + 8 + q,  N_EDGE + 3)];
            int2 f1e = csr2[min(i + 12 + q, N_EDGE + 3)];
            float v0 = (i + q < end)     ? 1.0f : 0.0f;
            float v1 = (i + 4 + q < end) ? 1.0f : 0.0f;

            unsigned ey0 = (unsigned)e0.y, ey1 = (unsigned)e1.y;
            float al0 = v0 * h2f(ey0 & 0xFFFFu);
            float al1 = v1 * h2f(ey1 & 0xFFFFu);

            uint2 uh0 = *(const uint2*)(hB    + (size_t)e0.x        * DIM + f0);
            uint2 ur0 = *(const uint2*)(relab + (size_t)(ey0 >> 16) * DIM + f0);
            uint2 uh1 = *(const uint2*)(hB    + (size_t)e1.x        * DIM + f0);
            uint2 ur1 = *(const uint2*)(relab + (size_t)(ey1 >> 16) * DIM + f0);

            acc.x = fmaf(al0, bflo(uh0.x) + bflo(ur0.x), acc.x);
            acc.y = fmaf(al0, bfhi(uh0.x) + bfhi(ur0.x), acc.y);
            acc.z = fmaf(al0, bflo(uh0.y) + bflo(ur0.y), acc.z);
            acc.w = fmaf(al0, bfhi(uh0.y) + bfhi(ur0.y), acc.w);
            acc.x = fmaf(al1, bflo(uh1.x) + bflo(ur1.x), acc.x);
            acc.y = fmaf(al1, bfhi(uh1.x) + bfhi(ur1.x), acc.y);
            acc.z = fmaf(al1, bflo(uh1.y) + bflo(ur1.y), acc.z);
            acc.w = fmaf(al1, bfhi(uh1.y) + bfhi(ur1.y), acc.w);

            e0 = f0e; e1 = f1e;
            i += 8;
        }

        acc.x += __shfl_xor(acc.x, 16); acc.x += __shfl_xor(acc.x, 32);
        acc.y += __shfl_xor(acc.y, 16); acc.y += __shfl_xor(acc.y, 32);
        acc.z += __shfl_xor(acc.z, 16); acc.z += __shfl_xor(acc.z, 32);
        acc.w += __shfl_xor(acc.w, 16); acc.w += __shfl_xor(acc.w, 32);
        if (q == 0)
            *(float4*)(out + (size_t)n * DIM + f0) = acc;

        i = ni; end = ne;
    }
}

// ---------------------------------------------------------------------------
// Fallback (ws too small for CSR): wave-per-edge atomic kernel, bf16 tables.
// ---------------------------------------------------------------------------
__global__ __launch_bounds__(256) void edge_kernel(
    const int*      __restrict__ edges,
    const ushort_t* __restrict__ hB,
    const ushort_t* __restrict__ relab,
    const ushort_t* __restrict__ hsWs,
    const ushort_t* __restrict__ rel_preb,
    const ushort_t* __restrict__ qr_preb,
    const float*    __restrict__ wattn,
    float* __restrict__ out)
{
    int e = (blockIdx.x * blockDim.x + threadIdx.x) >> 6;
    if (e >= N_EDGE) return;
    int lane = threadIdx.x & 63;
    int r_i = edges[e * 6 + 0];
    int rl  = edges[e * 6 + 2];
    int sb  = edges[e * 6 + 4];
    int ob  = edges[e * 6 + 5];
    float hs = __uint_as_float(((unsigned)hB[(size_t)sb * DIM + lane]) << 16);
    float hr = __uint_as_float(((unsigned)relab[(size_t)rl * DIM + lane]) << 16);
    float p1 = __uint_as_float(((unsigned)hsWs[(size_t)sb * DIM + lane]) << 16);
    float p2 = __uint_as_float(((unsigned)rel_preb[(size_t)rl * DIM + lane]) << 16);
    float p3 = __uint_as_float(((unsigned)qr_preb[(size_t)r_i * DIM + lane]) << 16);
    float t = wattn[lane] * fmaxf(p1 + p2 + p3, 0.0f);
    #pragma unroll
    for (int off = 32; off; off >>= 1) t += __shfl_xor(t, off);
    float alpha = 1.0f / (1.0f + __expf(-t));
    atomicAdd(&out[(size_t)ob * DIM + lane], (hs + hr) * alpha);
}

extern "C" void kernel_launch(void* const* d_in, const int* in_sizes, int n_in,
                              void* d_out, int out_size, void* d_ws, size_t ws_size,
                              hipStream_t stream)
{
    const float* hidden = (const float*)d_in[0];
    const int*   q_rel  = (const int*)  d_in[1];
    const int*   edges  = (const int*)  d_in[2];
    const float* rela   = (const float*)d_in[3];
    const float* Ws     = (const float*)d_in[4];
    const float* Wr     = (const float*)d_in[5];
    const float* Wqr    = (const float*)d_in[6];
    const float* Wqr_b  = (const float*)d_in[7];
    const float* Wattn  = (const float*)d_in[8];
    const float* Wh     = (const float*)d_in[9];
    float* out = (float*)d_out;

    // ---- workspace layout ----
    ushort_t* qr_preb  = (ushort_t*)d_ws;                 // 256*64 bf16
    ushort_t* rel_preb = qr_preb + NB * DIM;              // 401*64 bf16
    ushort_t* relab    = rel_preb + NVOCAB * DIM;         // 401*64 bf16
    ushort_t* hsWs     = relab + NVOCAB * DIM;            // 100000*64 bf16
    ushort_t* hidb     = hsWs + (size_t)N_NODE * DIM;     // 100000*64 bf16
    int* rank    = (int*)(hidb + (size_t)N_NODE * DIM);   // N_EDGE
    int* deg     = rank + N_EDGE;                         // N_NODE
    int* offs    = deg + N_NODE;                          // N_NODE+1
    int* partial = offs + (N_NODE + 1);                   // 128 slots
    int* csr_raw = partial + 128;
    int2* csr2   = (int2*)(((uintptr_t)csr_raw + 7) & ~(uintptr_t)7);
    size_t csr_need = ((char*)csr2 - (char*)d_ws) + (size_t)(N_EDGE + 4) * sizeof(int2);
    bool use_csr = ws_size >= csr_need;

    if (use_csr) {
        hipMemsetAsync(deg, 0, N_NODE * sizeof(int), stream);
        // one launch: 3 gemms + deg/rank, Bresenham-interleaved for co-residency
        prep_kernel<<<PREP_GRID, 256, 0, stream>>>(
            hidden, rela, q_rel, Ws, Wr, Wqr, Wqr_b,
            hsWs, hidb, rel_preb, relab, qr_preb, edges, deg, rank);
        scan1_kernel<<<NCHUNK, SCAN_B, 0, stream>>>(deg, partial);
        scan2_kernel<<<1, 128, 0, stream>>>(partial, NCHUNK);
        scan3_kernel<<<NCHUNK, SCAN_B, 0, stream>>>(deg, partial, offs);
        // 64 edges per block (4 waves x 4 quarters x 4 edges); exact division
        alpha_scatter_kernel<<<N_EDGE / 64, 256, 0, stream>>>(
            edges, rank, offs, hsWs, rel_preb, qr_preb, Wattn, csr2);
        agg_kernel<<<AGG_WAVES / 4, 256, 0, stream>>>(csr2, offs, hidb, relab, out);
    } else {
        gemm64_kernel<<<(NVOCAB + 63) / 64, 256, 0, stream>>>(
            rela, nullptr, Wr, nullptr, rel_preb, relab, NVOCAB, 3);
        gemm64_kernel<<<(NB + 63) / 64, 256, 0, stream>>>(
            rela, q_rel, Wqr, Wqr_b, qr_preb, nullptr, NB, 2);
        gemm64_kernel<<<(N_NODE + 63) / 64, 256, 0, stream>>>(
            hidden, nullptr, Ws, nullptr, hsWs, hidb, N_NODE, 3);
        hipMemsetAsync(d_out, 0, (size_t)N_NODE * DIM * sizeof(float), stream);
        edge_kernel<<<(N_EDGE + 3) / 4, 256, 0, stream>>>(
            edges, hidb, relab, hsWs, rel_preb, qr_preb, Wattn, out);
    }

    // ---- out = relu(agg @ Wh^T), in-place ----
    gemm64_kernel<<<(N_NODE + 63) / 64, 256, 0, stream>>>(
        out, nullptr, Wh, nullptr, out, nullptr, N_NODE, 1);
}

// Round 11
// 258.027 us; speedup vs baseline: 2.6396x; 1.0306x over previous
//
#include <hip/hip_runtime.h>
#include <math.h>
#include <stdint.h>

#define N_NODE 100000
#define N_EDGE 1000000
#define DIM    64
#define NB     256
#define NVOCAB 401
#define SCAN_B 1024
#define NCHUNK ((N_NODE + SCAN_B - 1) / SCAN_B)
#define AGG_WAVES 8192
#define NSHARD 8
#define EPB 2048            // edges per deg block (256 thr x 8)

typedef short short8  __attribute__((ext_vector_type(8)));
typedef float floatx4 __attribute__((ext_vector_type(4)));
typedef unsigned short ushort_t;

__device__ inline unsigned short f2bf_rne(float f)
{
    unsigned u = __float_as_uint(f);
    unsigned r = u + 0x7FFF + ((u >> 16) & 1);
    return (unsigned short)(r >> 16);
}
__device__ inline float bflo(unsigned u) { return __uint_as_float(u << 16); }
__device__ inline float bfhi(unsigned u) { return __uint_as_float(u & 0xFFFF0000u); }
__device__ inline unsigned short f2h(float f)
{
    _Float16 h = (_Float16)f;
    unsigned short s; __builtin_memcpy(&s, &h, 2); return s;
}
__device__ inline float h2f(unsigned b)
{
    unsigned short s = (unsigned short)b;
    _Float16 h; __builtin_memcpy(&h, &s, 2); return (float)h;
}

// ---------------------------------------------------------------------------
// gemm64 body (fp32 A): Y[r][:] = act( X[idx?idx[r]:r] @ W^T + bias ).
// Split-bf16 (hi/lo) 3-MFMA => ~fp32 precision. 4 waves = 64 rows; wave w
// owns rows r0+16w..+15, all 64 cols. In-place safe per-wave.
// out_mode: 0 fp32 | 1 fp32+relu | 2 bf16 | 3 bf16 + bf16(X) copy to Y2.
// ---------------------------------------------------------------------------
__device__ inline void split8(float4 v0, float4 v1, short8& hi, short8& lo)
{
    float f[8] = {v0.x, v0.y, v0.z, v0.w, v1.x, v1.y, v1.z, v1.w};
    #pragma unroll
    for (int j = 0; j < 8; ++j) {
        unsigned u = __float_as_uint(f[j]);
        unsigned r = u + 0x7FFF + ((u >> 16) & 1);
        unsigned short h = (unsigned short)(r >> 16);
        float hf = __uint_as_float(((unsigned)h) << 16);
        float l  = f[j] - hf;
        unsigned u2 = __float_as_uint(l);
        unsigned r2 = u2 + 0x7FFF + ((u2 >> 16) & 1);
        hi[j] = (short)h;
        lo[j] = (short)(r2 >> 16);
    }
}

__device__ void gemm64_body(
    const float* __restrict__ X,
    const int*   __restrict__ idx,
    const float* __restrict__ W,
    const float* __restrict__ bias,
    void* __restrict__ Yv,
    ushort_t* __restrict__ Y2,
    int R, int out_mode, int blk)
{
    int wave = threadIdx.x >> 6;
    int lane = threadIdx.x & 63;
    int m    = lane & 15;
    int quad = lane >> 4;
    int r0   = blk * 64 + wave * 16;

    int r = r0 + m;
    int src = (r < R) ? (idx ? idx[r] : r) : 0;
    const float* xrow = X + (size_t)src * DIM + quad * 8;

    float4 a0[2], a1[2];
    #pragma unroll
    for (int c = 0; c < 2; ++c) {
        a0[c] = *(const float4*)(xrow + 32 * c);
        a1[c] = *(const float4*)(xrow + 32 * c + 4);
    }
    short8 ah[2], al[2];
    #pragma unroll
    for (int c = 0; c < 2; ++c) split8(a0[c], a1[c], ah[c], al[c]);

    if (out_mode == 3 && r < R) {
        #pragma unroll
        for (int c = 0; c < 2; ++c)
            *(short8*)(Y2 + (size_t)r * DIM + 32 * c + quad * 8) = ah[c];
    }

    floatx4 acc[4] = {{0,0,0,0},{0,0,0,0},{0,0,0,0},{0,0,0,0}};
    #pragma unroll
    for (int g = 0; g < 4; ++g) {
        const float* wrow = W + (size_t)(g * 16 + m) * DIM + quad * 8;
        #pragma unroll
        for (int c = 0; c < 2; ++c) {
            float4 b0 = *(const float4*)(wrow + 32 * c);
            float4 b1 = *(const float4*)(wrow + 32 * c + 4);
            short8 bh, bl;
            split8(b0, b1, bh, bl);
            acc[g] = __builtin_amdgcn_mfma_f32_16x16x32_bf16(ah[c], bh, acc[g], 0, 0, 0);
            acc[g] = __builtin_amdgcn_mfma_f32_16x16x32_bf16(ah[c], bl, acc[g], 0, 0, 0);
            acc[g] = __builtin_amdgcn_mfma_f32_16x16x32_bf16(al[c], bh, acc[g], 0, 0, 0);
        }
    }

    #pragma unroll
    for (int g = 0; g < 4; ++g) {
        float bv = bias ? bias[g * 16 + m] : 0.0f;
        #pragma unroll
        for (int reg = 0; reg < 4; ++reg) {
            int rr = r0 + quad * 4 + reg;
            if (rr < R) {
                float v = acc[g][reg] + bv;
                if (out_mode == 1) v = fmaxf(v, 0.0f);
                if (out_mode >= 2)
                    ((ushort_t*)Yv)[(size_t)rr * DIM + g * 16 + m] = f2bf_rne(v);
                else
                    ((float*)Yv)[(size_t)rr * DIM + g * 16 + m] = v;
            }
        }
    }
}

__global__ __launch_bounds__(256) void gemm64_kernel(
    const float* __restrict__ X, const int* __restrict__ idx,
    const float* __restrict__ W, const float* __restrict__ bias,
    void* __restrict__ Yv, ushort_t* __restrict__ Y2, int R, int out_mode)
{
    gemm64_body(X, idx, W, bias, Yv, Y2, R, out_mode, blockIdx.x);
}

// ---------------------------------------------------------------------------
// Final gemm, bf16 A input: Y[r] = relu( A[r] @ W^T ), A bf16, W fp32-split,
// output fp32. 16 MFMA/block-row vs 24 (A has no lo part).
// ---------------------------------------------------------------------------
__global__ __launch_bounds__(256) void gemm64_bf16A_kernel(
    const ushort_t* __restrict__ A,
    const float* __restrict__ W,
    float* __restrict__ Y, int R)
{
    int wave = threadIdx.x >> 6;
    int lane = threadIdx.x & 63;
    int m    = lane & 15;
    int quad = lane >> 4;
    int r0   = blockIdx.x * 64 + wave * 16;

    int r = r0 + m;
    int src = (r < R) ? r : 0;
    short8 a8[2];
    #pragma unroll
    for (int c = 0; c < 2; ++c)
        a8[c] = *(const short8*)(A + (size_t)src * DIM + 32 * c + quad * 8);

    floatx4 acc[4] = {{0,0,0,0},{0,0,0,0},{0,0,0,0},{0,0,0,0}};
    #pragma unroll
    for (int g = 0; g < 4; ++g) {
        const float* wrow = W + (size_t)(g * 16 + m) * DIM + quad * 8;
        #pragma unroll
        for (int c = 0; c < 2; ++c) {
            float4 b0 = *(const float4*)(wrow + 32 * c);
            float4 b1 = *(const float4*)(wrow + 32 * c + 4);
            short8 bh, bl;
            split8(b0, b1, bh, bl);
            acc[g] = __builtin_amdgcn_mfma_f32_16x16x32_bf16(a8[c], bh, acc[g], 0, 0, 0);
            acc[g] = __builtin_amdgcn_mfma_f32_16x16x32_bf16(a8[c], bl, acc[g], 0, 0, 0);
        }
    }

    #pragma unroll
    for (int g = 0; g < 4; ++g) {
        #pragma unroll
        for (int reg = 0; reg < 4; ++reg) {
            int rr = r0 + quad * 4 + reg;
            if (rr < R)
                Y[(size_t)rr * DIM + g * 16 + m] = fmaxf(acc[g][reg], 0.0f);
        }
    }
}

// ---------------------------------------------------------------------------
// prep: ONE launch. Blocks 0..10: small rel/qr gemms. Rest interleaves
// hsWs-gemm blocks with deg/rank/epack blocks (Bresenham). Deg counters are
// SHARDED 8x by edge-chunk (cuts same-address atomic serialization 8x) and
// each deg thread carries 8 independent atomic RTs. Deg path also emits
// epack[e] = (sub|rel<<17, obj|r_idx<<17) -- 8B/edge, so alpha_scatter never
// touches the 24B-stride edges array again.
// ---------------------------------------------------------------------------
#define G1 ((N_NODE + 63) / 64)            // 1563
#define G2 ((NVOCAB + 63) / 64)            // 7
#define G3 (NB / 64)                       // 4
#define GSMALL (G2 + G3)                   // 11
#define GD8 ((N_EDGE + EPB - 1) / EPB)     // 489
#define PREP_T (G1 + GD8)                  // 2052
#define PREP_GRID (GSMALL + PREP_T)

__global__ __launch_bounds__(256) void prep_kernel(
    const float* __restrict__ hidden,
    const float* __restrict__ rela,
    const int*   __restrict__ q_rel,
    const float* __restrict__ Ws,
    const float* __restrict__ Wr,
    const float* __restrict__ Wqr,
    const float* __restrict__ Wqr_b,
    ushort_t* __restrict__ hsWs,
    ushort_t* __restrict__ hidb,
    ushort_t* __restrict__ rel_preb,
    ushort_t* __restrict__ relab,
    ushort_t* __restrict__ qr_preb,
    const int* __restrict__ edges,
    int* __restrict__ deg8,        // [8][N_NODE], pre-zeroed
    int* __restrict__ rank,
    int2* __restrict__ epack)
{
    int b = blockIdx.x;
    if (b < G2) {
        gemm64_body(rela, nullptr, Wr, nullptr, rel_preb, relab, NVOCAB, 3, b);
    } else if (b < GSMALL) {
        gemm64_body(rela, q_rel, Wqr, Wqr_b, qr_preb, nullptr, NB, 2, b - G2);
    } else {
        int bp = b - GSMALL;
        int prior = (int)(((long)bp * GD8) / PREP_T);
        int nxt   = (int)(((long)(bp + 1) * GD8) / PREP_T);
        if (nxt > prior) {
            int base = prior * EPB + threadIdx.x;
            #pragma unroll
            for (int k = 0; k < 8; ++k) {
                int e = base + k * 256;
                if (e < N_EDGE) {
                    int2 ab = *(const int2*)(edges + (size_t)e * 6);      // (r_idx,0)
                    int2 cd = *(const int2*)(edges + (size_t)e * 6 + 2);  // (rel,0)
                    int2 ef = *(const int2*)(edges + (size_t)e * 6 + 4);  // (sub,obj)
                    epack[e] = make_int2(ef.x | (cd.x << 17), ef.y | (ab.x << 17));
                    int s = (e >> 11) & (NSHARD - 1);
                    rank[e] = atomicAdd(&deg8[s * N_NODE + ef.y], 1);
                }
            }
        } else {
            gemm64_body(hidden, nullptr, Ws, nullptr, hsWs, hidb, N_NODE, 3, bp - prior);
        }
    }
}

// ---------------------------------------------------------------------------
// CSR scan pipeline over sharded counters.
// ---------------------------------------------------------------------------
__global__ __launch_bounds__(SCAN_B) void scan1_kernel(const int* __restrict__ deg8,
                                                       int* __restrict__ partial)
{
    __shared__ int s[SCAN_B];
    int g = blockIdx.x * SCAN_B + threadIdx.x;
    int tot = 0;
    if (g < N_NODE)
        #pragma unroll
        for (int k = 0; k < NSHARD; ++k) tot += deg8[k * N_NODE + g];
    s[threadIdx.x] = tot;
    __syncthreads();
    for (int off = SCAN_B / 2; off; off >>= 1) {
        if (threadIdx.x < off) s[threadIdx.x] += s[threadIdx.x + off];
        __syncthreads();
    }
    if (threadIdx.x == 0) partial[blockIdx.x] = s[0];
}

__global__ __launch_bounds__(128) void scan2_kernel(int* __restrict__ partial, int n)
{
    __shared__ int s[128];
    int t = threadIdx.x;
    int v = (t < n) ? partial[t] : 0;
    s[t] = v;
    __syncthreads();
    for (int off = 1; off < 128; off <<= 1) {
        int add = (t >= off) ? s[t - off] : 0;
        __syncthreads();
        s[t] += add;
        __syncthreads();
    }
    if (t < n) partial[t] = s[t] - v;   // exclusive
}

// scan3: offs[g+1] = global inclusive; also rewrites deg8 IN PLACE into
// per-shard slot bases: deg8[s][g] <- offs[g] + sum_{s'<s} deg_s'(g).
__global__ __launch_bounds__(SCAN_B) void scan3_kernel(int* __restrict__ deg8,
                                                       const int* __restrict__ partial,
                                                       int* __restrict__ offs)
{
    __shared__ int s[SCAN_B];
    int g = blockIdx.x * SCAN_B + threadIdx.x;
    int d[NSHARD];
    int tot = 0;
    if (g < N_NODE) {
        #pragma unroll
        for (int k = 0; k < NSHARD; ++k) { d[k] = deg8[k * N_NODE + g]; tot += d[k]; }
    }
    s[threadIdx.x] = tot;
    __syncthreads();
    for (int off = 1; off < SCAN_B; off <<= 1) {
        int add = ((int)threadIdx.x >= off) ? s[threadIdx.x - off] : 0;
        __syncthreads();
        s[threadIdx.x] += add;
        __syncthreads();
    }
    if (g < N_NODE) {
        int incl = partial[blockIdx.x] + s[threadIdx.x];
        offs[g + 1] = incl;
        if (g == 0) offs[0] = 0;
        int run = incl - tot;                     // = offs[g]
        #pragma unroll
        for (int k = 0; k < NSHARD; ++k) { deg8[k * N_NODE + g] = run; run += d[k]; }
    }
}

// ---------------------------------------------------------------------------
// alpha + scatter v3: reads only epack (8B coalesced) + rank + bf16 tables.
// Quarter-wave, 4 edges/quarter, 64 edges/block (exact: N_EDGE = 64*15625).
// slot = base8[shard(e)][obj] + rank[e]; atomic-free.
// ---------------------------------------------------------------------------
__global__ __launch_bounds__(256) void alpha_scatter_kernel(
    const int2*     __restrict__ epack,
    const int*      __restrict__ rank,
    const int*      __restrict__ base8,     // deg8 transformed by scan3
    const ushort_t* __restrict__ hsWs,
    const ushort_t* __restrict__ rel_preb,
    const ushort_t* __restrict__ qr_preb,
    const float*    __restrict__ wattn,
    int2*           __restrict__ csr2)
{
    int tid = blockIdx.x * 256 + threadIdx.x;
    if (tid < 4) csr2[N_EDGE + tid] = make_int2(0, 0);

    int wave = threadIdx.x >> 6;
    int lane = threadIdx.x & 63;
    int q    = lane >> 4;
    int l    = lane & 15;
    int f0   = l * 4;
    int e0   = (blockIdx.x * 4 + wave) * 16 + q * 4;

    float4 wa = *(const float4*)(wattn + f0);

    int   sub[4], rl[4], ob[4];
    float t[4];
    #pragma unroll
    for (int j = 0; j < 4; ++j) {
        int e = e0 + j;
        int2 ep = epack[e];
        sub[j] = ep.x & 0x1FFFF;
        rl[j]  = (int)((unsigned)ep.x >> 17);
        ob[j]  = ep.y & 0x1FFFF;
        int ri = (int)((unsigned)ep.y >> 17);

        uint2 uh = *(const uint2*)(hsWs     + (size_t)sub[j] * DIM + f0);
        uint2 ur = *(const uint2*)(rel_preb + (size_t)rl[j]  * DIM + f0);
        uint2 uq = *(const uint2*)(qr_preb  + (size_t)ri     * DIM + f0);

        float tt =  fmaxf(bflo(uh.x) + bflo(ur.x) + bflo(uq.x), 0.f) * wa.x;
        tt = fmaf(fmaxf(bfhi(uh.x) + bfhi(ur.x) + bfhi(uq.x), 0.f), wa.y, tt);
        tt = fmaf(fmaxf(bflo(uh.y) + bflo(ur.y) + bflo(uq.y), 0.f), wa.z, tt);
        tt = fmaf(fmaxf(bfhi(uh.y) + bfhi(ur.y) + bfhi(uq.y), 0.f), wa.w, tt);
        t[j] = tt;
    }
    #pragma unroll
    for (int j = 0; j < 4; ++j) {
        t[j] += __shfl_xor(t[j], 1);
        t[j] += __shfl_xor(t[j], 2);
        t[j] += __shfl_xor(t[j], 4);
        t[j] += __shfl_xor(t[j], 8);
    }

    if (l == 0) {
        int4 rk = *(const int4*)(rank + e0);
        int rka[4] = {rk.x, rk.y, rk.z, rk.w};
        int sh = (e0 >> 11) & (NSHARD - 1);      // all 4 edges share a 2048-chunk
        #pragma unroll
        for (int j = 0; j < 4; ++j) {
            float alpha = 1.0f / (1.0f + __expf(-t[j]));
            int slot = base8[sh * N_NODE + ob[j]] + rka[j];
            csr2[slot] = make_int2(sub[j],
                (int)(((unsigned)rl[j] << 16) | f2h(alpha)));
        }
    }
}

// ---------------------------------------------------------------------------
// Aggregation v6: persistent waves, 8 edges/iter, bf16 OUTPUT (halves write).
// ---------------------------------------------------------------------------
__global__ __launch_bounds__(256) void agg_kernel(
    const int2*     __restrict__ csr2,
    const int*      __restrict__ offs,
    const ushort_t* __restrict__ hB,
    const ushort_t* __restrict__ relab,
    ushort_t* __restrict__ aggb)         // bf16 [N_NODE][64]
{
    int lane = threadIdx.x & 63;
    int q    = lane >> 4;
    int l    = lane & 15;
    int f0   = l * 4;
    int wv = __builtin_amdgcn_readfirstlane((blockIdx.x * blockDim.x + threadIdx.x) >> 6);

    int i   = offs[wv];
    int end = offs[wv + 1];
    for (int n = wv; n < N_NODE; n += AGG_WAVES) {
        int nn = n + AGG_WAVES;
        int ni = 0, ne = 0;
        if (nn < N_NODE) { ni = offs[nn]; ne = offs[nn + 1]; }

        float4 acc = make_float4(0.f, 0.f, 0.f, 0.f);
        int2 e0 = csr2[min(i + q,     N_EDGE + 3)];
        int2 e1 = csr2[min(i + 4 + q, N_EDGE + 3)];
        while (i < end) {
            int2 f0e = csr2[min(i + 8 + q,  N_EDGE + 3)];
            int2 f1e = csr2[min(i + 12 + q, N_EDGE + 3)];
            float v0 = (i + q < end)     ? 1.0f : 0.0f;
            float v1 = (i + 4 + q < end) ? 1.0f : 0.0f;

            unsigned ey0 = (unsigned)e0.y, ey1 = (unsigned)e1.y;
            float al0 = v0 * h2f(ey0 & 0xFFFFu);
            float al1 = v1 * h2f(ey1 & 0xFFFFu);

            uint2 uh0 = *(const uint2*)(hB    + (size_t)e0.x        * DIM + f0);
            uint2 ur0 = *(const uint2*)(relab + (size_t)(ey0 >> 16) * DIM + f0);
            uint2 uh1 = *(const uint2*)(hB    + (size_t)e1.x        * DIM + f0);
            uint2 ur1 = *(const uint2*)(relab + (size_t)(ey1 >> 16) * DIM + f0);

            acc.x = fmaf(al0, bflo(uh0.x) + bflo(ur0.x), acc.x);
            acc.y = fmaf(al0, bfhi(uh0.x) + bfhi(ur0.x), acc.y);
            acc.z = fmaf(al0, bflo(uh0.y) + bflo(ur0.y), acc.z);
            acc.w = fmaf(al0, bfhi(uh0.y) + bfhi(ur0.y), acc.w);
            acc.x = fmaf(al1, bflo(uh1.x) + bflo(ur1.x), acc.x);
            acc.y = fmaf(al1, bfhi(uh1.x) + bfhi(ur1.x), acc.y);
            acc.z = fmaf(al1, bflo(uh1.y) + bflo(ur1.y), acc.z);
            acc.w = fmaf(al1, bfhi(uh1.y) + bfhi(ur1.y), acc.w);

            e0 = f0e; e1 = f1e;
            i += 8;
        }

        acc.x += __shfl_xor(acc.x, 16); acc.x += __shfl_xor(acc.x, 32);
        acc.y += __shfl_xor(acc.y, 16); acc.y += __shfl_xor(acc.y, 32);
        acc.z += __shfl_xor(acc.z, 16); acc.z += __shfl_xor(acc.z, 32);
        acc.w += __shfl_xor(acc.w, 16); acc.w += __shfl_xor(acc.w, 32);
        if (q == 0) {
            uint2 o;
            o.x = (unsigned)f2bf_rne(acc.x) | ((unsigned)f2bf_rne(acc.y) << 16);
            o.y = (unsigned)f2bf_rne(acc.z) | ((unsigned)f2bf_rne(acc.w) << 16);
            *(uint2*)(aggb + (size_t)n * DIM + f0) = o;
        }

        i = ni; end = ne;
    }
}

// ---------------------------------------------------------------------------
// Fallback (ws too small): wave-per-edge atomic kernel, bf16 tables.
// ---------------------------------------------------------------------------
__global__ __launch_bounds__(256) void edge_kernel(
    const int*      __restrict__ edges,
    const ushort_t* __restrict__ hB,
    const ushort_t* __restrict__ relab,
    const ushort_t* __restrict__ hsWs,
    const ushort_t* __restrict__ rel_preb,
    const ushort_t* __restrict__ qr_preb,
    const float*    __restrict__ wattn,
    float* __restrict__ out)
{
    int e = (blockIdx.x * blockDim.x + threadIdx.x) >> 6;
    if (e >= N_EDGE) return;
    int lane = threadIdx.x & 63;
    int r_i = edges[e * 6 + 0];
    int rl  = edges[e * 6 + 2];
    int sb  = edges[e * 6 + 4];
    int ob  = edges[e * 6 + 5];
    float hs = __uint_as_float(((unsigned)hB[(size_t)sb * DIM + lane]) << 16);
    float hr = __uint_as_float(((unsigned)relab[(size_t)rl * DIM + lane]) << 16);
    float p1 = __uint_as_float(((unsigned)hsWs[(size_t)sb * DIM + lane]) << 16);
    float p2 = __uint_as_float(((unsigned)rel_preb[(size_t)rl * DIM + lane]) << 16);
    float p3 = __uint_as_float(((unsigned)qr_preb[(size_t)r_i * DIM + lane]) << 16);
    float t = wattn[lane] * fmaxf(p1 + p2 + p3, 0.0f);
    #pragma unroll
    for (int off = 32; off; off >>= 1) t += __shfl_xor(t, off);
    float alpha = 1.0f / (1.0f + __expf(-t));
    atomicAdd(&out[(size_t)ob * DIM + lane], (hs + hr) * alpha);
}

extern "C" void kernel_launch(void* const* d_in, const int* in_sizes, int n_in,
                              void* d_out, int out_size, void* d_ws, size_t ws_size,
                              hipStream_t stream)
{
    const float* hidden = (const float*)d_in[0];
    const int*   q_rel  = (const int*)  d_in[1];
    const int*   edges  = (const int*)  d_in[2];
    const float* rela   = (const float*)d_in[3];
    const float* Ws     = (const float*)d_in[4];
    const float* Wr     = (const float*)d_in[5];
    const float* Wqr    = (const float*)d_in[6];
    const float* Wqr_b  = (const float*)d_in[7];
    const float* Wattn  = (const float*)d_in[8];
    const float* Wh     = (const float*)d_in[9];
    float* out = (float*)d_out;

    // ---- workspace layout ----
    ushort_t* qr_preb  = (ushort_t*)d_ws;                 // 256*64 bf16
    ushort_t* rel_preb = qr_preb + NB * DIM;              // 401*64 bf16
    ushort_t* relab    = rel_preb + NVOCAB * DIM;         // 401*64 bf16
    ushort_t* hsWs     = relab + NVOCAB * DIM;            // 100000*64 bf16
    ushort_t* hidb     = hsWs + (size_t)N_NODE * DIM;     // 100000*64 bf16
    int2* epack  = (int2*)(((uintptr_t)(hidb + (size_t)N_NODE * DIM) + 15) & ~(uintptr_t)15);
    int*  rank   = (int*)(epack + N_EDGE);                // N_EDGE
    int*  deg8   = rank + N_EDGE;                         // 8*N_NODE
    int*  offs   = deg8 + NSHARD * N_NODE;                // N_NODE+1
    int*  partial= offs + (N_NODE + 1);                   // 128
    int2* csr2   = (int2*)(((uintptr_t)(partial + 128) + 15) & ~(uintptr_t)15);
    size_t csr_need = ((char*)(csr2 + N_EDGE + 4)) - (char*)d_ws;
    bool use_csr = ws_size >= csr_need;
    // aggb aliases the dead epack/rank/deg8 region (15.2MB >= 12.8MB needed);
    // epack/rank/deg8 are dead after alpha_scatter; csr2/offs stay intact.
    ushort_t* aggb = (ushort_t*)epack;

    if (use_csr) {
        hipMemsetAsync(deg8, 0, NSHARD * N_NODE * sizeof(int), stream);
        prep_kernel<<<PREP_GRID, 256, 0, stream>>>(
            hidden, rela, q_rel, Ws, Wr, Wqr, Wqr_b,
            hsWs, hidb, rel_preb, relab, qr_preb, edges, deg8, rank, epack);
        scan1_kernel<<<NCHUNK, SCAN_B, 0, stream>>>(deg8, partial);
        scan2_kernel<<<1, 128, 0, stream>>>(partial, NCHUNK);
        scan3_kernel<<<NCHUNK, SCAN_B, 0, stream>>>(deg8, partial, offs);
        alpha_scatter_kernel<<<N_EDGE / 64, 256, 0, stream>>>(
            epack, rank, deg8, hsWs, rel_preb, qr_preb, Wattn, csr2);
        agg_kernel<<<AGG_WAVES / 4, 256, 0, stream>>>(csr2, offs, hidb, relab, aggb);
        gemm64_bf16A_kernel<<<(N_NODE + 63) / 64, 256, 0, stream>>>(aggb, Wh, out, N_NODE);
    } else {
        gemm64_kernel<<<(NVOCAB + 63) / 64, 256, 0, stream>>>(
            rela, nullptr, Wr, nullptr, rel_preb, relab, NVOCAB, 3);
        gemm64_kernel<<<(NB + 63) / 64, 256, 0, stream>>>(
            rela, q_rel, Wqr, Wqr_b, qr_preb, nullptr, NB, 2);
        gemm64_kernel<<<(N_NODE + 63) / 64, 256, 0, stream>>>(
            hidden, nullptr, Ws, nullptr, hsWs, hidb, N_NODE, 3);
        hipMemsetAsync(d_out, 0, (size_t)N_NODE * DIM * sizeof(float), stream);
        edge_kernel<<<(N_EDGE + 3) / 4, 256, 0, stream>>>(
            edges, hidb, relab, hsWs, rel_preb, qr_preb, Wattn, out);
        gemm64_kernel<<<(N_NODE + 63) / 64, 256, 0, stream>>>(
            out, nullptr, Wh, nullptr, out, nullptr, N_NODE, 1);
    }
}